// Round 3
// baseline (673.611 us; speedup 1.0000x reference)
//
#include <hip/hip_runtime.h>
#include <math.h>

#define BQ 4
#define DM 192
#define DI 384
#define HH 48
#define WW 48
#define LL 2304
#define KK 4
#define NN 16
#define RR 12
#define CH 48      // chunks per sequence
#define CLEN 48    // chunk length (mult of 16; l0 % 48 == 0 for pos logic)
#define NBATCH 3   // CLEN/16

__device__ __forceinline__ float gelu_exact(float x) {
    return 0.5f * x * (1.0f + erff(x * 0.7071067811865476f));
}

__device__ __forceinline__ float softplus_f(float x) {
    return fmaxf(x, 0.0f) + log1pf(expf(-fabsf(x)));
}

__device__ __forceinline__ int pos_for(int k, int l) {
    if (k == 0) return l;
    if (k == 1) { return (l % HH) * WW + (l / HH); }
    if (k == 2) return (LL - 1) - l;
    int j = (LL - 1) - l;
    return (j % HH) * WW + (j / HH);
}

// DPP move: 0x00-0xFF quad_perm; 0xB1 = quad xor1, 0x4E = quad xor2.
template<int CTRL>
__device__ __forceinline__ float dpp_movf(float v) {
    return __int_as_float(__builtin_amdgcn_update_dpp(
        0, __float_as_int(v), CTRL, 0xF, 0xF, true));
}

// ---------------- K0: negA = -exp(A_logs)
__global__ __launch_bounds__(256) void k_prep(const float* __restrict__ Alogs,
                                              float* __restrict__ negA) {
    int i = blockIdx.x * 256 + threadIdx.x;
    if (i < KK * DI * NN) negA[i] = -expf(Alogs[i]);
}

// ---------------- K1: in_proj 1x1 (768x192 GEMM), split -> xc_pre, gelu(z)->z1
__global__ __launch_bounds__(256) void k_inproj(const float* __restrict__ x,
                                                const float* __restrict__ w,
                                                float* __restrict__ xc_pre,
                                                float* __restrict__ z1) {
    __shared__ float xt[16 * 193];
    const int nt = LL / 16;
    int b = blockIdx.x / nt;
    int l0 = (blockIdx.x % nt) * 16;
    int tid = threadIdx.x;
    for (int idx = tid; idx < DM * 16; idx += 256) {
        int lt = idx & 15, d = idx >> 4;
        xt[lt * 193 + d] = x[(size_t)(b * DM + d) * LL + l0 + lt];
    }
    __syncthreads();
    for (int pass = 0; pass < 12; ++pass) {
        int t = pass * 256 + tid;
        int o = t >> 2, ltq = t & 3;
        float s0 = 0.f, s1 = 0.f, s2 = 0.f, s3 = 0.f;
        const float* wr = w + (size_t)o * DM;
        int base = (ltq * 4) * 193;
        for (int d = 0; d < DM; ++d) {
            float wv = wr[d];
            s0 += wv * xt[base + d];
            s1 += wv * xt[base + 193 + d];
            s2 += wv * xt[base + 2 * 193 + d];
            s3 += wv * xt[base + 3 * 193 + d];
        }
        int l = l0 + ltq * 4;
        if (o < DI) {
            float* p = xc_pre + (size_t)(b * DI + o) * LL + l;
            p[0] = s0; p[1] = s1; p[2] = s2; p[3] = s3;
        } else {
            int oz = o - DI;
            float* p = z1 + (size_t)(b * LL + l) * DI + oz;
            p[0]        = gelu_exact(s0);
            p[DI]       = gelu_exact(s1);
            p[2 * DI]   = gelu_exact(s2);
            p[3 * DI]   = gelu_exact(s3);
        }
    }
}

// ---------------- K2: depthwise 3x3 conv + bias + gelu
__global__ __launch_bounds__(256) void k_dwconv(const float* __restrict__ xc_pre,
                                                const float* __restrict__ cw,
                                                const float* __restrict__ cb,
                                                float* __restrict__ xc_conv) {
    int idx = blockIdx.x * 256 + threadIdx.x;
    if (idx >= BQ * DI * LL) return;
    int l = idx % LL;
    int tmp = idx / LL;
    int c = tmp % DI;
    int b = tmp / DI;
    int h = l / WW, w = l % WW;
    const float* in = xc_pre + (size_t)(b * DI + c) * LL;
    const float* k9 = cw + c * 9;
    float s = cb[c];
    #pragma unroll
    for (int dh = -1; dh <= 1; ++dh) {
        int hh = h + dh;
        if (hh < 0 || hh >= HH) continue;
        #pragma unroll
        for (int dw = -1; dw <= 1; ++dw) {
            int ww = w + dw;
            if (ww < 0 || ww >= WW) continue;
            s += in[hh * WW + ww] * k9[(dh + 1) * 3 + (dw + 1)];
        }
    }
    xc_conv[idx] = gelu_exact(s);
}

// ---------------- K3: x_proj per direction -> dts (B,K,L,R), Bs/Cs (B,K,L,N)
__global__ __launch_bounds__(256) void k_xproj(const float* __restrict__ xc_conv,
                                               const float* __restrict__ xpw,
                                               float* __restrict__ dts,
                                               float* __restrict__ Bsb,
                                               float* __restrict__ Csb) {
    __shared__ float xt[16 * 385];
    const int nt = LL / 16;
    int l0 = (blockIdx.x % nt) * 16;
    int bk = blockIdx.x / nt;
    int k = bk % KK;
    int b = bk / KK;
    for (int idx = threadIdx.x; idx < DI * 16; idx += 256) {
        int lt = idx & 15, d = idx >> 4;
        int pos = pos_for(k, l0 + lt);
        xt[lt * 385 + d] = xc_conv[(size_t)(b * DI + d) * LL + pos];
    }
    __syncthreads();
    int t = threadIdx.x;
    if (t < 176) {
        int c = t >> 2, ltq = t & 3;
        float s0 = 0.f, s1 = 0.f, s2 = 0.f, s3 = 0.f;
        const float* wr = xpw + (size_t)(k * 44 + c) * DI;
        int base = (ltq * 4) * 385;
        for (int d = 0; d < DI; ++d) {
            float wv = wr[d];
            s0 += wv * xt[base + d];
            s1 += wv * xt[base + 385 + d];
            s2 += wv * xt[base + 2 * 385 + d];
            s3 += wv * xt[base + 3 * 385 + d];
        }
        float sv[4] = {s0, s1, s2, s3};
        #pragma unroll
        for (int j = 0; j < 4; ++j) {
            int l = l0 + ltq * 4 + j;
            if (c < RR)
                dts[((size_t)bk * LL + l) * RR + c] = sv[j];
            else if (c < RR + NN)
                Bsb[((size_t)bk * LL + l) * NN + (c - RR)] = sv[j];
            else
                Csb[((size_t)bk * LL + l) * NN + (c - RR - NN)] = sv[j];
        }
    }
}

// ---------------- Single-pass chunked scan (h from 0).
// Emits: y_loc (+u*D) via fused cross-merge atomics, inclusive delta-cumsum
// S[bk][l][d], and chunk end-states hst. Correction for true h_in is applied
// later by k_corr_ln_gate (fully parallel).
__global__ __launch_bounds__(256) void k_scan_pass1(
    const float* __restrict__ xc_conv,
    const float* __restrict__ dts,
    const float* __restrict__ Bsb,
    const float* __restrict__ Csb,
    const float* __restrict__ dtw_g,
    const float* __restrict__ dtb_g,
    const float* __restrict__ negA,
    const float* __restrict__ Ds_g,
    float* __restrict__ Sbuf,
    float* __restrict__ hst,
    float* __restrict__ ym)
{
    int blk = blockIdx.x;                 // ((bk*CH + c)*6 + dblk)
    int dblk = blk % 6;
    int tmp = blk / 6;
    int c = tmp % CH;
    int bk = tmp / CH;
    int k = bk & 3, b = bk >> 2;
    int tid = threadIdx.x;
    int lane = tid & 63, wv = tid >> 6;
    int q = lane & 3;
    int d16 = lane >> 2;
    int d = dblk * 64 + wv * 16 + d16;
    int kd = k * DI + d;
    int n0 = q << 2;

    float4 A4 = *(const float4*)(negA + (size_t)kd * NN + n0);
    float A[4] = { A4.x, A4.y, A4.z, A4.w };
    float dtb = dtb_g[kd];
    float dtw[12];
    {
        const float4* p = (const float4*)(dtw_g + (size_t)kd * RR);
        float4 a0 = p[0], a1 = p[1], a2 = p[2];
        dtw[0]=a0.x; dtw[1]=a0.y; dtw[2]=a0.z;  dtw[3]=a0.w;
        dtw[4]=a1.x; dtw[5]=a1.y; dtw[6]=a1.z;  dtw[7]=a1.w;
        dtw[8]=a2.x; dtw[9]=a2.y; dtw[10]=a2.z; dtw[11]=a2.w;
    }
    const float* up  = xc_conv + (size_t)(b * DI + d) * LL;
    const float* dtp = dts + (size_t)bk * LL * RR;
    const float* Bp  = Bsb + (size_t)bk * LL * NN;
    const float* Cp  = Csb + (size_t)bk * LL * NN;
    float* Sb_p = Sbuf + (size_t)bk * LL * DI;

    int l0 = c * CLEN;
    float h[4] = {0.f, 0.f, 0.f, 0.f};
    float Dv = Ds_g[kd];
    float* ymp = ym + (size_t)b * LL * DI;
    int pos = pos_for(k, l0);
    int cnt = 0;                          // l0 % 48 == 0
    float td = 0.f;

    for (int g = 0; g < NBATCH; ++g) {
        int lb = l0 + g * 16;
        float deltab[4], ub[4];
        #pragma unroll
        for (int i = 0; i < 4; ++i) {
            int lme = lb + n0 + i;
            const float4* dp4 = (const float4*)(dtp + (size_t)lme * RR);
            float4 x0 = dp4[0], x1 = dp4[1], x2 = dp4[2];
            float acc = dtb
                + x0.x*dtw[0] + x0.y*dtw[1] + x0.z*dtw[2]  + x0.w*dtw[3]
                + x1.x*dtw[4] + x1.y*dtw[5] + x1.z*dtw[6]  + x1.w*dtw[7]
                + x2.x*dtw[8] + x2.y*dtw[9] + x2.z*dtw[10] + x2.w*dtw[11];
            deltab[i] = softplus_f(acc);
            ub[i] = up[pos_for(k, lme)];
        }

#define SSTEP(J) { \
        constexpr int S_ = (J) >> 2, I_ = (J) & 3; \
        float delta = dpp_movf<S_ * 0x55>(deltab[I_]); \
        float ub_b  = dpp_movf<S_ * 0x55>(ub[I_]); \
        td += delta; \
        float du = delta * ub_b; \
        float4 B4 = *(const float4*)(Bp + (size_t)(lb + (J)) * NN + n0); \
        float dA0 = __expf(delta * A[0]); h[0] = h[0] * dA0 + du * B4.x; \
        float dA1 = __expf(delta * A[1]); h[1] = h[1] * dA1 + du * B4.y; \
        float dA2 = __expf(delta * A[2]); h[2] = h[2] * dA2 + du * B4.z; \
        float dA3 = __expf(delta * A[3]); h[3] = h[3] * dA3 + du * B4.w; \
        float4 C4 = *(const float4*)(Cp + (size_t)(lb + (J)) * NN + n0); \
        float yp = h[0]*C4.x + h[1]*C4.y + h[2]*C4.z + h[3]*C4.w; \
        yp += dpp_movf<0xB1>(yp); \
        yp += dpp_movf<0x4E>(yp); \
        if (q == 0) { \
            atomicAdd(&ymp[(size_t)pos * DI + d], yp + ub_b * Dv); \
            Sb_p[(size_t)(lb + (J)) * DI + d] = td; \
        } \
        if (k == 0) pos += 1; \
        else if (k == 2) pos -= 1; \
        else { \
            bool wr_ = (cnt == 47); \
            if (k == 1) pos += wr_ ? -2255 : 48; \
            else        pos += wr_ ? 2255 : -48; \
            cnt = wr_ ? 0 : cnt + 1; \
        } }

        SSTEP(0)  SSTEP(1)  SSTEP(2)  SSTEP(3)
        SSTEP(4)  SSTEP(5)  SSTEP(6)  SSTEP(7)
        SSTEP(8)  SSTEP(9)  SSTEP(10) SSTEP(11)
        SSTEP(12) SSTEP(13) SSTEP(14) SSTEP(15)
#undef SSTEP
    }

    float4 h4; h4.x = h[0]; h4.y = h[1]; h4.z = h[2]; h4.w = h[3];
    *(float4*)(hst + ((size_t)(bk * CH + c) * DI + d) * NN + n0) = h4;
}

// ---------------- combine: sequential over CH chunks per (bk,d,n)
__global__ __launch_bounds__(256) void k_scan_combine(
    const float* __restrict__ hst,
    const float* __restrict__ Sbuf,
    const float* __restrict__ negA,
    float* __restrict__ hin)
{
    int t = blockIdx.x * 256 + threadIdx.x;   // B*K*DI*NN = 98304
    int n = t & 15;
    int d = (t >> 4) % DI;
    int bk = t / (DI * NN);
    int k = bk & 3;
    float A = negA[(size_t)(k * DI + d) * NN + n];
    float h = 0.f;
    for (int c = 0; c < CH; ++c) {
        size_t rb = (size_t)(bk * CH + c) * DI + d;
        hin[rb * NN + n] = h;
        float St = Sbuf[((size_t)bk * LL + c * CLEN + CLEN - 1) * DI + d];
        h = __expf(A * St) * h + hst[rb * NN + n];
    }
}

// ---------------- correction + LayerNorm + gate, one block per (b,pos)
__global__ __launch_bounds__(384) void k_corr_ln_gate(
    const float* __restrict__ ym,
    const float* __restrict__ Csb,
    const float* __restrict__ Sbuf,
    const float* __restrict__ hin,
    const float* __restrict__ negA,
    const float* __restrict__ z1,
    const float* __restrict__ lnw,
    const float* __restrict__ lnb,
    float* __restrict__ gbuf)
{
    int pg = blockIdx.x;            // b*LL + pos
    int b = pg / LL;
    int pos = pg % LL;
    int d = threadIdx.x;
    int pt = (pos % 48) * 48 + pos / 48;

    float acc = ym[(size_t)pg * DI + d];
    #pragma unroll
    for (int k = 0; k < 4; ++k) {
        int l = (k == 0) ? pos : (k == 1) ? pt
              : (k == 2) ? (LL - 1 - pos) : (LL - 1 - pt);
        int bk = b * 4 + k;
        int c = l / CLEN;
        float S = Sbuf[((size_t)bk * LL + l) * DI + d];
        const float4* hp = (const float4*)(hin + ((size_t)(bk * CH + c) * DI + d) * NN);
        const float4* Cq = (const float4*)(Csb + ((size_t)bk * LL + l) * NN);
        const float4* Ap = (const float4*)(negA + ((size_t)k * DI + d) * NN);
        #pragma unroll
        for (int j = 0; j < 4; ++j) {
            float4 Cv = Cq[j], Hv = hp[j], Av = Ap[j];
            acc += Cv.x * __expf(Av.x * S) * Hv.x
                 + Cv.y * __expf(Av.y * S) * Hv.y
                 + Cv.z * __expf(Av.z * S) * Hv.z
                 + Cv.w * __expf(Av.w * S) * Hv.w;
        }
    }

    float s = acc, qq = acc * acc;
    #pragma unroll
    for (int o = 32; o >= 1; o >>= 1) {
        s += __shfl_xor(s, o, 64);
        qq += __shfl_xor(qq, o, 64);
    }
    __shared__ float ssum[6], sqq[6];
    int lane = d & 63, w = d >> 6;
    if (lane == 0) { ssum[w] = s; sqq[w] = qq; }
    __syncthreads();
    float ts = 0.f, tq = 0.f;
    #pragma unroll
    for (int i = 0; i < 6; ++i) { ts += ssum[i]; tq += sqq[i]; }
    float mu = ts / (float)DI;
    float var = tq / (float)DI - mu * mu;
    float inv = rsqrtf(var + 1e-5f);
    float y = (acc - mu) * inv * lnw[d] + lnb[d];
    gbuf[(size_t)pg * DI + d] = y * z1[(size_t)pg * DI + d];
}

// ---------------- K6: out_proj 1x1 (192x384 GEMM)
__global__ __launch_bounds__(256) void k_outproj(const float* __restrict__ gbuf,
                                                 const float* __restrict__ w,
                                                 float* __restrict__ out) {
    __shared__ float xt[16 * 385];
    const int nt = LL / 16;
    int b = blockIdx.x / nt;
    int l0 = (blockIdx.x % nt) * 16;
    for (int idx = threadIdx.x; idx < DI * 16; idx += 256) {
        int d = idx % DI;
        int lt = idx / DI;
        xt[lt * 385 + d] = gbuf[(size_t)(b * LL + l0 + lt) * DI + d];
    }
    __syncthreads();
    for (int pass = 0; pass < 3; ++pass) {
        int t = pass * 256 + threadIdx.x;
        int o = t >> 2, ltq = t & 3;
        float s0 = 0.f, s1 = 0.f, s2 = 0.f, s3 = 0.f;
        const float* wr = w + (size_t)o * DI;
        int base = (ltq * 4) * 385;
        for (int d = 0; d < DI; ++d) {
            float wv = wr[d];
            s0 += wv * xt[base + d];
            s1 += wv * xt[base + 385 + d];
            s2 += wv * xt[base + 2 * 385 + d];
            s3 += wv * xt[base + 3 * 385 + d];
        }
        float* p = out + (size_t)(b * DM + o) * LL + l0 + ltq * 4;
        p[0] = s0; p[1] = s1; p[2] = s2; p[3] = s3;
    }
}

extern "C" void kernel_launch(void* const* d_in, const int* in_sizes, int n_in,
                              void* d_out, int out_size, void* d_ws, size_t ws_size,
                              hipStream_t stream) {
    (void)in_sizes; (void)n_in; (void)out_size; (void)ws_size;
    const float* x      = (const float*)d_in[0];
    const float* ipw    = (const float*)d_in[1];
    const float* cw     = (const float*)d_in[2];
    const float* cb     = (const float*)d_in[3];
    const float* xpw    = (const float*)d_in[4];
    const float* dtw    = (const float*)d_in[5];
    const float* dtb    = (const float*)d_in[6];
    const float* Alogs  = (const float*)d_in[7];
    const float* Ds     = (const float*)d_in[8];
    const float* lnw    = (const float*)d_in[9];
    const float* lnb    = (const float*)d_in[10];
    const float* opw    = (const float*)d_in[11];
    float* out = (float*)d_out;

    float* wsf = (float*)d_ws;
    const size_t SZ  = (size_t)BQ * DI * LL;              // 3,538,944
    const size_t DTS = (size_t)BQ * KK * LL * RR;         // 442,368
    const size_t BCS = (size_t)BQ * KK * LL * NN;         // 589,824
    const size_t SBF = (size_t)BQ * KK * LL * DI;         // 14,155,776
    const size_t HST = (size_t)BQ * KK * CH * DI * NN;    // 4,718,592

    float* z1      = wsf;                 // (B,L,DI)
    float* xc_pre  = z1 + SZ;             // (B,DI,L); reused as gbuf
    float* xc_conv = xc_pre + SZ;         // (B,DI,L)
    float* dts     = xc_conv + SZ;        // (B,K,L,R)
    float* Bsb     = dts + DTS;           // (B,K,L,N)
    float* Csb     = Bsb + BCS;           // (B,K,L,N)
    float* ym      = Csb + BCS;           // (B,L,DI)
    float* Sbuf    = ym + SZ;             // (B,K,L,DI) inclusive delta cumsum
    float* hst     = Sbuf + SBF;          // (B,K,CH,DI,N) chunk end-states
    float* hin     = hst + HST;           // (B,K,CH,DI,N) chunk incoming states
    float* negA    = hin + HST;           // (K,DI,N)
    float* gbuf    = xc_pre;

    k_prep<<<(KK * DI * NN + 255) / 256, 256, 0, stream>>>(Alogs, negA);
    k_inproj<<<BQ * (LL / 16), 256, 0, stream>>>(x, ipw, xc_pre, z1);
    k_dwconv<<<(BQ * DI * LL) / 256, 256, 0, stream>>>(xc_pre, cw, cb, xc_conv);
    k_xproj<<<BQ * KK * (LL / 16), 256, 0, stream>>>(xc_conv, xpw, dts, Bsb, Csb);

    hipMemsetAsync(ym, 0, SZ * sizeof(float), stream);
    k_scan_pass1<<<BQ * KK * CH * 6, 256, 0, stream>>>(
        xc_conv, dts, Bsb, Csb, dtw, dtb, negA, Ds, Sbuf, hst, ym);
    k_scan_combine<<<(BQ * KK * DI * NN) / 256, 256, 0, stream>>>(
        hst, Sbuf, negA, hin);
    k_corr_ln_gate<<<BQ * LL, 384, 0, stream>>>(
        ym, Csb, Sbuf, hin, negA, z1, lnw, lnb, gbuf);

    k_outproj<<<BQ * (LL / 16), 256, 0, stream>>>(gbuf, opw, out);
}

// Round 4
// 630.798 us; speedup vs baseline: 1.0679x; 1.0679x over previous
//
#include <hip/hip_runtime.h>
#include <math.h>

#define BQ 4
#define DM 192
#define DI 384
#define HH 48
#define WW 48
#define LL 2304
#define KK 4
#define NN 16
#define RR 12
#define CH 48      // chunks per sequence
#define CLEN 48    // chunk length (mult of 16; CLEN multiple-of-48 keeps cnt=0 at chunk start)
#define NBATCH 3   // CLEN/16

__device__ __forceinline__ float gelu_exact(float x) {
    return 0.5f * x * (1.0f + erff(x * 0.7071067811865476f));
}

__device__ __forceinline__ float softplus_f(float x) {
    return fmaxf(x, 0.0f) + log1pf(expf(-fabsf(x)));
}

__device__ __forceinline__ int pos_for(int k, int l) {
    if (k == 0) return l;
    if (k == 1) { return (l % HH) * WW + (l / HH); }
    if (k == 2) return (LL - 1) - l;
    int j = (LL - 1) - l;
    return (j % HH) * WW + (j / HH);
}

// DPP move: 0x00-0xFF quad_perm; 0xB1 = quad xor1, 0x4E = quad xor2.
template<int CTRL>
__device__ __forceinline__ float dpp_movf(float v) {
    return __int_as_float(__builtin_amdgcn_update_dpp(
        0, __float_as_int(v), CTRL, 0xF, 0xF, true));
}

// ---------------- K1: in_proj 1x1 (768x192 GEMM), split -> xc_pre, gelu(z)->z1
__global__ __launch_bounds__(256) void k_inproj(const float* __restrict__ x,
                                                const float* __restrict__ w,
                                                float* __restrict__ xc_pre,
                                                float* __restrict__ z1) {
    __shared__ float xt[16 * 193];
    const int nt = LL / 16;
    int b = blockIdx.x / nt;
    int l0 = (blockIdx.x % nt) * 16;
    int tid = threadIdx.x;
    for (int idx = tid; idx < DM * 16; idx += 256) {
        int lt = idx & 15, d = idx >> 4;
        xt[lt * 193 + d] = x[(size_t)(b * DM + d) * LL + l0 + lt];
    }
    __syncthreads();
    for (int pass = 0; pass < 12; ++pass) {
        int t = pass * 256 + tid;
        int o = t >> 2, ltq = t & 3;
        float s0 = 0.f, s1 = 0.f, s2 = 0.f, s3 = 0.f;
        const float* wr = w + (size_t)o * DM;
        int base = (ltq * 4) * 193;
        for (int d = 0; d < DM; ++d) {
            float wv = wr[d];
            s0 += wv * xt[base + d];
            s1 += wv * xt[base + 193 + d];
            s2 += wv * xt[base + 2 * 193 + d];
            s3 += wv * xt[base + 3 * 193 + d];
        }
        int l = l0 + ltq * 4;
        if (o < DI) {
            float* p = xc_pre + (size_t)(b * DI + o) * LL + l;
            p[0] = s0; p[1] = s1; p[2] = s2; p[3] = s3;
        } else {
            int oz = o - DI;
            float* p = z1 + (size_t)(b * LL + l) * DI + oz;
            p[0]        = gelu_exact(s0);
            p[DI]       = gelu_exact(s1);
            p[2 * DI]   = gelu_exact(s2);
            p[3 * DI]   = gelu_exact(s3);
        }
    }
}

// ---------------- K2: depthwise 3x3 conv + bias + gelu
__global__ __launch_bounds__(256) void k_dwconv(const float* __restrict__ xc_pre,
                                                const float* __restrict__ cw,
                                                const float* __restrict__ cb,
                                                float* __restrict__ xc_conv) {
    int idx = blockIdx.x * 256 + threadIdx.x;
    if (idx >= BQ * DI * LL) return;
    int l = idx % LL;
    int tmp = idx / LL;
    int c = tmp % DI;
    int b = tmp / DI;
    int h = l / WW, w = l % WW;
    const float* in = xc_pre + (size_t)(b * DI + c) * LL;
    const float* k9 = cw + c * 9;
    float s = cb[c];
    #pragma unroll
    for (int dh = -1; dh <= 1; ++dh) {
        int hh = h + dh;
        if (hh < 0 || hh >= HH) continue;
        #pragma unroll
        for (int dw = -1; dw <= 1; ++dw) {
            int ww = w + dw;
            if (ww < 0 || ww >= WW) continue;
            s += in[hh * WW + ww] * k9[(dh + 1) * 3 + (dw + 1)];
        }
    }
    xc_conv[idx] = gelu_exact(s);
}

// ---------------- K3: x_proj per direction -> dts (B,K,L,R), Bs/Cs (B,K,L,N)
__global__ __launch_bounds__(256) void k_xproj(const float* __restrict__ xc_conv,
                                               const float* __restrict__ xpw,
                                               float* __restrict__ dts,
                                               float* __restrict__ Bsb,
                                               float* __restrict__ Csb) {
    __shared__ float xt[16 * 385];
    const int nt = LL / 16;
    int l0 = (blockIdx.x % nt) * 16;
    int bk = blockIdx.x / nt;
    int k = bk % KK;
    int b = bk / KK;
    for (int idx = threadIdx.x; idx < DI * 16; idx += 256) {
        int lt = idx & 15, d = idx >> 4;
        int pos = pos_for(k, l0 + lt);
        xt[lt * 385 + d] = xc_conv[(size_t)(b * DI + d) * LL + pos];
    }
    __syncthreads();
    int t = threadIdx.x;
    if (t < 176) {
        int c = t >> 2, ltq = t & 3;
        float s0 = 0.f, s1 = 0.f, s2 = 0.f, s3 = 0.f;
        const float* wr = xpw + (size_t)(k * 44 + c) * DI;
        int base = (ltq * 4) * 385;
        for (int d = 0; d < DI; ++d) {
            float wv = wr[d];
            s0 += wv * xt[base + d];
            s1 += wv * xt[base + 385 + d];
            s2 += wv * xt[base + 2 * 385 + d];
            s3 += wv * xt[base + 3 * 385 + d];
        }
        float sv[4] = {s0, s1, s2, s3};
        #pragma unroll
        for (int j = 0; j < 4; ++j) {
            int l = l0 + ltq * 4 + j;
            if (c < RR)
                dts[((size_t)bk * LL + l) * RR + c] = sv[j];
            else if (c < RR + NN)
                Bsb[((size_t)bk * LL + l) * NN + (c - RR)] = sv[j];
            else
                Csb[((size_t)bk * LL + l) * NN + (c - RR - NN)] = sv[j];
        }
    }
}

// ---------------- Single-pass chunked scan (h from 0).
// Emits y_loc (+u*D) via fused cross-merge atomics, inclusive delta-cumsum
// S[bk][l][d], and chunk end-states hst. Correction applied by k_corr.
__global__ __launch_bounds__(256) void k_scan_pass1(
    const float* __restrict__ xc_conv,
    const float* __restrict__ dts,
    const float* __restrict__ Bsb,
    const float* __restrict__ Csb,
    const float* __restrict__ dtw_g,
    const float* __restrict__ dtb_g,
    const float* __restrict__ Alogs,
    const float* __restrict__ Ds_g,
    float* __restrict__ Sbuf,
    float* __restrict__ hst,
    float* __restrict__ ym)
{
    int blk = blockIdx.x;                 // ((bk*CH + c)*6 + dblk)
    int dblk = blk % 6;
    int tmp = blk / 6;
    int c = tmp % CH;
    int bk = tmp / CH;
    int k = bk & 3, b = bk >> 2;
    int tid = threadIdx.x;
    int lane = tid & 63, wv = tid >> 6;
    int q = lane & 3;
    int d16 = lane >> 2;
    int d = dblk * 64 + wv * 16 + d16;
    int kd = k * DI + d;
    int n0 = q << 2;

    float4 Al = *(const float4*)(Alogs + (size_t)kd * NN + n0);
    float A[4] = { -expf(Al.x), -expf(Al.y), -expf(Al.z), -expf(Al.w) };
    float dtb = dtb_g[kd];
    float dtw[12];
    {
        const float4* p = (const float4*)(dtw_g + (size_t)kd * RR);
        float4 a0 = p[0], a1 = p[1], a2 = p[2];
        dtw[0]=a0.x; dtw[1]=a0.y; dtw[2]=a0.z;  dtw[3]=a0.w;
        dtw[4]=a1.x; dtw[5]=a1.y; dtw[6]=a1.z;  dtw[7]=a1.w;
        dtw[8]=a2.x; dtw[9]=a2.y; dtw[10]=a2.z; dtw[11]=a2.w;
    }
    const float* up  = xc_conv + (size_t)(b * DI + d) * LL;
    const float* dtp = dts + (size_t)bk * LL * RR;
    const float* Bp  = Bsb + (size_t)bk * LL * NN;
    const float* Cp  = Csb + (size_t)bk * LL * NN;
    float* Sb_p = Sbuf + (size_t)bk * LL * DI;

    int l0 = c * CLEN;
    float h[4] = {0.f, 0.f, 0.f, 0.f};
    float Dv = Ds_g[kd];
    float* ymp = ym + (size_t)b * LL * DI;
    int pos = pos_for(k, l0);
    int cnt = l0 % 48;
    float td = 0.f;

    for (int g = 0; g < NBATCH; ++g) {
        int lb = l0 + g * 16;
        float deltab[4], ub[4];
        #pragma unroll
        for (int i = 0; i < 4; ++i) {
            int lme = lb + n0 + i;
            const float4* dp4 = (const float4*)(dtp + (size_t)lme * RR);
            float4 x0 = dp4[0], x1 = dp4[1], x2 = dp4[2];
            float acc = dtb
                + x0.x*dtw[0] + x0.y*dtw[1] + x0.z*dtw[2]  + x0.w*dtw[3]
                + x1.x*dtw[4] + x1.y*dtw[5] + x1.z*dtw[6]  + x1.w*dtw[7]
                + x2.x*dtw[8] + x2.y*dtw[9] + x2.z*dtw[10] + x2.w*dtw[11];
            deltab[i] = softplus_f(acc);
            ub[i] = up[pos_for(k, lme)];
        }

#define SSTEP(J) { \
        constexpr int S_ = (J) >> 2, I_ = (J) & 3; \
        float delta = dpp_movf<S_ * 0x55>(deltab[I_]); \
        float ub_b  = dpp_movf<S_ * 0x55>(ub[I_]); \
        td += delta; \
        float du = delta * ub_b; \
        float4 B4 = *(const float4*)(Bp + (size_t)(lb + (J)) * NN + n0); \
        float dA0 = __expf(delta * A[0]); h[0] = h[0] * dA0 + du * B4.x; \
        float dA1 = __expf(delta * A[1]); h[1] = h[1] * dA1 + du * B4.y; \
        float dA2 = __expf(delta * A[2]); h[2] = h[2] * dA2 + du * B4.z; \
        float dA3 = __expf(delta * A[3]); h[3] = h[3] * dA3 + du * B4.w; \
        float4 C4 = *(const float4*)(Cp + (size_t)(lb + (J)) * NN + n0); \
        float yp = h[0]*C4.x + h[1]*C4.y + h[2]*C4.z + h[3]*C4.w; \
        yp += dpp_movf<0xB1>(yp); \
        yp += dpp_movf<0x4E>(yp); \
        if (q == 0) { \
            atomicAdd(&ymp[(size_t)pos * DI + d], yp + ub_b * Dv); \
            Sb_p[(size_t)(lb + (J)) * DI + d] = td; \
        } \
        if (k == 0) pos += 1; \
        else if (k == 2) pos -= 1; \
        else { \
            bool wr_ = (cnt == 47); \
            if (k == 1) pos += wr_ ? -2255 : 48; \
            else        pos += wr_ ? 2255 : -48; \
            cnt = wr_ ? 0 : cnt + 1; \
        } }

        SSTEP(0)  SSTEP(1)  SSTEP(2)  SSTEP(3)
        SSTEP(4)  SSTEP(5)  SSTEP(6)  SSTEP(7)
        SSTEP(8)  SSTEP(9)  SSTEP(10) SSTEP(11)
        SSTEP(12) SSTEP(13) SSTEP(14) SSTEP(15)
#undef SSTEP
    }

    float4 h4; h4.x = h[0]; h4.y = h[1]; h4.z = h[2]; h4.w = h[3];
    *(float4*)(hst + ((size_t)(bk * CH + c) * DI + d) * NN + n0) = h4;
}

// ---------------- combine: sequential over CH chunks per (bk,d,n)
__global__ __launch_bounds__(256) void k_scan_combine(
    const float* __restrict__ hst,
    const float* __restrict__ Sbuf,
    const float* __restrict__ Alogs,
    float* __restrict__ hin)
{
    int t = blockIdx.x * 256 + threadIdx.x;   // B*K*DI*NN = 98304
    int n = t & 15;
    int d = (t >> 4) % DI;
    int bk = t / (DI * NN);
    int k = bk & 3;
    float A = -expf(Alogs[(size_t)(k * DI + d) * NN + n]);
    float h = 0.f;
    for (int c = 0; c < CH; ++c) {
        size_t rb = (size_t)(bk * CH + c) * DI + d;
        hin[rb * NN + n] = h;
        float St = Sbuf[((size_t)bk * LL + c * CLEN + CLEN - 1) * DI + d];
        h = __expf(A * St) * h + hst[rb * NN + n];
    }
}

// ---------------- correction: chunk-local, hin in registers, atomics into ym
__global__ __launch_bounds__(256) void k_corr(
    const float* __restrict__ Csb,
    const float* __restrict__ Sbuf,
    const float* __restrict__ hin,
    const float* __restrict__ Alogs,
    float* __restrict__ ym)
{
    int blk = blockIdx.x;                 // ((bk*CH + c)*6 + dblk)
    int dblk = blk % 6;
    int tmp = blk / 6;
    int c = tmp % CH;
    if (c == 0) return;                   // h_in == 0 -> zero correction
    int bk = tmp / CH;
    int k = bk & 3, b = bk >> 2;
    int lane = threadIdx.x & 63, wv = threadIdx.x >> 6;
    int q = lane & 3;
    int d16 = lane >> 2;
    int d = dblk * 64 + wv * 16 + d16;
    int kd = k * DI + d;
    int n0 = q << 2;

    float4 Al = *(const float4*)(Alogs + (size_t)kd * NN + n0);
    float A[4] = { -expf(Al.x), -expf(Al.y), -expf(Al.z), -expf(Al.w) };
    float4 H4 = *(const float4*)(hin + ((size_t)(bk * CH + c) * DI + d) * NN + n0);
    const float* Cp = Csb + (size_t)bk * LL * NN;
    const float* Sp = Sbuf + (size_t)bk * LL * DI;
    float* ymp = ym + (size_t)b * LL * DI;

    int l0 = c * CLEN;
    int pos = pos_for(k, l0);
    int cnt = l0 % 48;
    for (int l = l0; l < l0 + CLEN; ++l) {
        float S = Sp[(size_t)l * DI + d];
        float4 C4 = *(const float4*)(Cp + (size_t)l * NN + n0);
        float yc = C4.x * __expf(A[0] * S) * H4.x
                 + C4.y * __expf(A[1] * S) * H4.y
                 + C4.z * __expf(A[2] * S) * H4.z
                 + C4.w * __expf(A[3] * S) * H4.w;
        yc += dpp_movf<0xB1>(yc);
        yc += dpp_movf<0x4E>(yc);
        if (q == 0) atomicAdd(&ymp[(size_t)pos * DI + d], yc);
        if (k == 0) pos += 1;
        else if (k == 2) pos -= 1;
        else {
            bool wr_ = (cnt == 47);
            if (k == 1) pos += wr_ ? -2255 : 48;
            else        pos += wr_ ? 2255 : -48;
            cnt = wr_ ? 0 : cnt + 1;
        }
    }
}

// ---------------- K5: LayerNorm over channel + gate with gelu(z)
__global__ __launch_bounds__(384) void k_ln_gate(const float* __restrict__ ym,
                                                 const float* __restrict__ z1,
                                                 const float* __restrict__ lnw,
                                                 const float* __restrict__ lnb,
                                                 float* __restrict__ gbuf) {
    int pos = blockIdx.x;
    int d = threadIdx.x;
    float v = ym[(size_t)pos * DI + d];
    float s = v, qq = v * v;
    #pragma unroll
    for (int o = 32; o >= 1; o >>= 1) {
        s += __shfl_xor(s, o, 64);
        qq += __shfl_xor(qq, o, 64);
    }
    __shared__ float ssum[6], sqq[6];
    int lane = d & 63, w = d >> 6;
    if (lane == 0) { ssum[w] = s; sqq[w] = qq; }
    __syncthreads();
    float ts = 0.f, tq = 0.f;
    #pragma unroll
    for (int i = 0; i < 6; ++i) { ts += ssum[i]; tq += sqq[i]; }
    float mu = ts / (float)DI;
    float var = tq / (float)DI - mu * mu;
    float inv = rsqrtf(var + 1e-5f);
    float y = (v - mu) * inv * lnw[d] + lnb[d];
    gbuf[(size_t)pos * DI + d] = y * z1[(size_t)pos * DI + d];
}

// ---------------- K6: out_proj 1x1 (192x384 GEMM)
__global__ __launch_bounds__(256) void k_outproj(const float* __restrict__ gbuf,
                                                 const float* __restrict__ w,
                                                 float* __restrict__ out) {
    __shared__ float xt[16 * 385];
    const int nt = LL / 16;
    int b = blockIdx.x / nt;
    int l0 = (blockIdx.x % nt) * 16;
    for (int idx = threadIdx.x; idx < DI * 16; idx += 256) {
        int d = idx % DI;
        int lt = idx / DI;
        xt[lt * 385 + d] = gbuf[(size_t)(b * LL + l0 + lt) * DI + d];
    }
    __syncthreads();
    for (int pass = 0; pass < 3; ++pass) {
        int t = pass * 256 + threadIdx.x;
        int o = t >> 2, ltq = t & 3;
        float s0 = 0.f, s1 = 0.f, s2 = 0.f, s3 = 0.f;
        const float* wr = w + (size_t)o * DI;
        int base = (ltq * 4) * 385;
        for (int d = 0; d < DI; ++d) {
            float wv = wr[d];
            s0 += wv * xt[base + d];
            s1 += wv * xt[base + 385 + d];
            s2 += wv * xt[base + 2 * 385 + d];
            s3 += wv * xt[base + 3 * 385 + d];
        }
        float* p = out + (size_t)(b * DM + o) * LL + l0 + ltq * 4;
        p[0] = s0; p[1] = s1; p[2] = s2; p[3] = s3;
    }
}

extern "C" void kernel_launch(void* const* d_in, const int* in_sizes, int n_in,
                              void* d_out, int out_size, void* d_ws, size_t ws_size,
                              hipStream_t stream) {
    (void)in_sizes; (void)n_in; (void)out_size; (void)ws_size;
    const float* x      = (const float*)d_in[0];
    const float* ipw    = (const float*)d_in[1];
    const float* cw     = (const float*)d_in[2];
    const float* cb     = (const float*)d_in[3];
    const float* xpw    = (const float*)d_in[4];
    const float* dtw    = (const float*)d_in[5];
    const float* dtb    = (const float*)d_in[6];
    const float* Alogs  = (const float*)d_in[7];
    const float* Ds     = (const float*)d_in[8];
    const float* lnw    = (const float*)d_in[9];
    const float* lnb    = (const float*)d_in[10];
    const float* opw    = (const float*)d_in[11];
    float* out = (float*)d_out;

    float* wsf = (float*)d_ws;
    const size_t SZ  = (size_t)BQ * DI * LL;              // 3,538,944
    const size_t DTS = (size_t)BQ * KK * LL * RR;
    const size_t BCS = (size_t)BQ * KK * LL * NN;
    const size_t SBF = (size_t)BQ * KK * LL * DI;         // 14,155,776
    const size_t HST = (size_t)BQ * KK * CH * DI * NN;    // 4,718,592

    float* z1      = wsf;                 // (B,L,DI)
    float* xc_pre  = z1 + SZ;             // (B,DI,L); reused as gbuf
    float* xc_conv = xc_pre + SZ;         // (B,DI,L)
    float* dts     = xc_conv + SZ;        // (B,K,L,R)
    float* Bsb     = dts + DTS;           // (B,K,L,N)
    float* Csb     = Bsb + BCS;           // (B,K,L,N)
    float* ym      = Csb + BCS;           // (B,L,DI)
    float* Sbuf    = ym + SZ;             // (B,K,L,DI)
    float* hst     = Sbuf + SBF;          // (B,K,CH,DI,N)
    float* hin     = hst + HST;           // (B,K,CH,DI,N)
    float* gbuf    = xc_pre;

    k_inproj<<<BQ * (LL / 16), 256, 0, stream>>>(x, ipw, xc_pre, z1);
    k_dwconv<<<(BQ * DI * LL) / 256, 256, 0, stream>>>(xc_pre, cw, cb, xc_conv);
    k_xproj<<<BQ * KK * (LL / 16), 256, 0, stream>>>(xc_conv, xpw, dts, Bsb, Csb);

    hipMemsetAsync(ym, 0, SZ * sizeof(float), stream);
    k_scan_pass1<<<BQ * KK * CH * 6, 256, 0, stream>>>(
        xc_conv, dts, Bsb, Csb, dtw, dtb, Alogs, Ds, Sbuf, hst, ym);
    k_scan_combine<<<(BQ * KK * DI * NN) / 256, 256, 0, stream>>>(
        hst, Sbuf, Alogs, hin);
    k_corr<<<BQ * KK * CH * 6, 256, 0, stream>>>(Csb, Sbuf, hin, Alogs, ym);
    k_ln_gate<<<BQ * LL, 384, 0, stream>>>(ym, z1, lnw, lnb, gbuf);

    k_outproj<<<BQ * (LL / 16), 256, 0, stream>>>(gbuf, opw, out);
}

// Round 5
// 563.143 us; speedup vs baseline: 1.1962x; 1.1201x over previous
//
#include <hip/hip_runtime.h>
#include <math.h>

#define BQ 4
#define DM 192
#define DI 384
#define HH 48
#define WW 48
#define LL 2304
#define KK 4
#define NN 16
#define RR 12
#define CH 48      // chunks per sequence
#define CLEN 48    // chunk length
#define NBATCH 3   // CLEN/16

__device__ __forceinline__ float gelu_exact(float x) {
    return 0.5f * x * (1.0f + erff(x * 0.7071067811865476f));
}

__device__ __forceinline__ float softplus_f(float x) {
    return fmaxf(x, 0.0f) + log1pf(expf(-fabsf(x)));
}

__device__ __forceinline__ int pos_for(int k, int l) {
    if (k == 0) return l;
    if (k == 1) { return (l % HH) * WW + (l / HH); }
    if (k == 2) return (LL - 1) - l;
    int j = (LL - 1) - l;
    return (j % HH) * WW + (j / HH);
}

// DPP move: 0x00-0xFF quad_perm; 0xB1 = quad xor1, 0x4E = quad xor2.
template<int CTRL>
__device__ __forceinline__ float dpp_movf(float v) {
    return __int_as_float(__builtin_amdgcn_update_dpp(
        0, __float_as_int(v), CTRL, 0xF, 0xF, true));
}

// ---------------- K1: in_proj 1x1 (768x192 GEMM), split -> xc_pre, gelu(z)->z1
__global__ __launch_bounds__(256) void k_inproj(const float* __restrict__ x,
                                                const float* __restrict__ w,
                                                float* __restrict__ xc_pre,
                                                float* __restrict__ z1) {
    __shared__ float xt[16 * 193];
    const int nt = LL / 16;
    int b = blockIdx.x / nt;
    int l0 = (blockIdx.x % nt) * 16;
    int tid = threadIdx.x;
    for (int idx = tid; idx < DM * 16; idx += 256) {
        int lt = idx & 15, d = idx >> 4;
        xt[lt * 193 + d] = x[(size_t)(b * DM + d) * LL + l0 + lt];
    }
    __syncthreads();
    for (int pass = 0; pass < 12; ++pass) {
        int t = pass * 256 + tid;
        int o = t >> 2, ltq = t & 3;
        float s0 = 0.f, s1 = 0.f, s2 = 0.f, s3 = 0.f;
        const float* wr = w + (size_t)o * DM;
        int base = (ltq * 4) * 193;
        for (int d = 0; d < DM; ++d) {
            float wv = wr[d];
            s0 += wv * xt[base + d];
            s1 += wv * xt[base + 193 + d];
            s2 += wv * xt[base + 2 * 193 + d];
            s3 += wv * xt[base + 3 * 193 + d];
        }
        int l = l0 + ltq * 4;
        if (o < DI) {
            float* p = xc_pre + (size_t)(b * DI + o) * LL + l;
            p[0] = s0; p[1] = s1; p[2] = s2; p[3] = s3;
        } else {
            int oz = o - DI;
            float* p = z1 + (size_t)(b * LL + l) * DI + oz;
            p[0]        = gelu_exact(s0);
            p[DI]       = gelu_exact(s1);
            p[2 * DI]   = gelu_exact(s2);
            p[3 * DI]   = gelu_exact(s3);
        }
    }
}

// ---------------- K2: depthwise 3x3 conv + bias + gelu, 4 outputs/thread
__global__ __launch_bounds__(256) void k_dwconv(const float* __restrict__ xc_pre,
                                                const float* __restrict__ cw,
                                                const float* __restrict__ cb,
                                                float* __restrict__ xc_conv) {
    int idx = blockIdx.x * 256 + threadIdx.x;          // B*DI*HH*12
    if (idx >= BQ * DI * HH * (WW / 4)) return;
    int wq = idx % 12;
    int w0 = wq * 4;
    int h = (idx / 12) % HH;
    int c = (idx / (12 * HH)) % DI;
    int b = idx / (12 * HH * DI);
    const float* in = xc_pre + (size_t)(b * DI + c) * LL;
    const float* k9 = cw + c * 9;
    float bias = cb[c];
    float s0 = bias, s1 = bias, s2 = bias, s3 = bias;
    #pragma unroll
    for (int dh = -1; dh <= 1; ++dh) {
        int hh = h + dh;
        if (hh < 0 || hh >= HH) continue;
        const float* r = in + hh * WW;
        float4 a = *(const float4*)(r + w0);
        float lft = (w0 > 0) ? r[w0 - 1] : 0.f;
        float rgt = (w0 + 4 < WW) ? r[w0 + 4] : 0.f;
        float k0 = k9[(dh + 1) * 3 + 0];
        float k1 = k9[(dh + 1) * 3 + 1];
        float k2 = k9[(dh + 1) * 3 + 2];
        s0 += k0 * lft + k1 * a.x + k2 * a.y;
        s1 += k0 * a.x + k1 * a.y + k2 * a.z;
        s2 += k0 * a.y + k1 * a.z + k2 * a.w;
        s3 += k0 * a.z + k1 * a.w + k2 * rgt;
    }
    float4 o;
    o.x = gelu_exact(s0); o.y = gelu_exact(s1);
    o.z = gelu_exact(s2); o.w = gelu_exact(s3);
    *(float4*)(xc_conv + (size_t)(b * DI + c) * LL + h * WW + w0) = o;
}

// ---------------- K3: x_proj per direction -> dts (B,K,L,R), Bs/Cs (B,K,L,N)
__global__ __launch_bounds__(256) void k_xproj(const float* __restrict__ xc_conv,
                                               const float* __restrict__ xpw,
                                               float* __restrict__ dts,
                                               float* __restrict__ Bsb,
                                               float* __restrict__ Csb) {
    __shared__ float xt[16 * 385];
    const int nt = LL / 16;
    int l0 = (blockIdx.x % nt) * 16;
    int bk = blockIdx.x / nt;
    int k = bk % KK;
    int b = bk / KK;
    for (int idx = threadIdx.x; idx < DI * 16; idx += 256) {
        int lt = idx & 15, d = idx >> 4;
        int pos = pos_for(k, l0 + lt);
        xt[lt * 385 + d] = xc_conv[(size_t)(b * DI + d) * LL + pos];
    }
    __syncthreads();
    int t = threadIdx.x;
    if (t < 176) {
        int c = t >> 2, ltq = t & 3;
        float s0 = 0.f, s1 = 0.f, s2 = 0.f, s3 = 0.f;
        const float* wr = xpw + (size_t)(k * 44 + c) * DI;
        int base = (ltq * 4) * 385;
        for (int d = 0; d < DI; ++d) {
            float wv = wr[d];
            s0 += wv * xt[base + d];
            s1 += wv * xt[base + 385 + d];
            s2 += wv * xt[base + 2 * 385 + d];
            s3 += wv * xt[base + 3 * 385 + d];
        }
        float sv[4] = {s0, s1, s2, s3};
        #pragma unroll
        for (int j = 0; j < 4; ++j) {
            int l = l0 + ltq * 4 + j;
            if (c < RR)
                dts[((size_t)bk * LL + l) * RR + c] = sv[j];
            else if (c < RR + NN)
                Bsb[((size_t)bk * LL + l) * NN + (c - RR)] = sv[j];
            else
                Csb[((size_t)bk * LL + l) * NN + (c - RR - NN)] = sv[j];
        }
    }
}

// ---------------- Single-pass chunked scan (h from 0). NO atomics:
// y_loc (+u*D) stored per-direction in scan order yk[bk][l][d] (plain coalesced
// stores, 1 store per lane per 4 steps via quad-banked yhold), plus inclusive
// delta-cumsum Sbuf[bk][l][d] and chunk end-states hstin.
__global__ __launch_bounds__(256) void k_scan_pass1(
    const float* __restrict__ xc_conv,
    const float* __restrict__ dts,
    const float* __restrict__ Bsb,
    const float* __restrict__ Csb,
    const float* __restrict__ dtw_g,
    const float* __restrict__ dtb_g,
    const float* __restrict__ Alogs,
    const float* __restrict__ Ds_g,
    float* __restrict__ Sbuf,
    float* __restrict__ hstin,
    float* __restrict__ yk)
{
    int blk = blockIdx.x;                 // ((bk*CH + c)*6 + dblk)
    int dblk = blk % 6;
    int tmp = blk / 6;
    int c = tmp % CH;
    int bk = tmp / CH;
    int k = bk & 3, b = bk >> 2;
    int tid = threadIdx.x;
    int lane = tid & 63, wv = tid >> 6;
    int q = lane & 3;
    int d16 = lane >> 2;
    int d = dblk * 64 + wv * 16 + d16;
    int kd = k * DI + d;
    int n0 = q << 2;

    float4 Al = *(const float4*)(Alogs + (size_t)kd * NN + n0);
    float A[4] = { -expf(Al.x), -expf(Al.y), -expf(Al.z), -expf(Al.w) };
    float dtb = dtb_g[kd];
    float dtw[12];
    {
        const float4* p = (const float4*)(dtw_g + (size_t)kd * RR);
        float4 a0 = p[0], a1 = p[1], a2 = p[2];
        dtw[0]=a0.x; dtw[1]=a0.y; dtw[2]=a0.z;  dtw[3]=a0.w;
        dtw[4]=a1.x; dtw[5]=a1.y; dtw[6]=a1.z;  dtw[7]=a1.w;
        dtw[8]=a2.x; dtw[9]=a2.y; dtw[10]=a2.z; dtw[11]=a2.w;
    }
    const float* up  = xc_conv + (size_t)(b * DI + d) * LL;
    const float* dtp = dts + (size_t)bk * LL * RR;
    const float* Bp  = Bsb + (size_t)bk * LL * NN;
    const float* Cp  = Csb + (size_t)bk * LL * NN;
    float* Sb_p = Sbuf + (size_t)bk * LL * DI;
    float* yk_p = yk + (size_t)bk * LL * DI;

    int l0 = c * CLEN;
    float h[4] = {0.f, 0.f, 0.f, 0.f};
    float Dv = Ds_g[kd];
    float td = 0.f;
    float yhold = 0.f, Shold = 0.f;

    for (int g = 0; g < NBATCH; ++g) {
        int lb = l0 + g * 16;
        float deltab[4], ub[4];
        #pragma unroll
        for (int i = 0; i < 4; ++i) {
            int lme = lb + n0 + i;
            const float4* dp4 = (const float4*)(dtp + (size_t)lme * RR);
            float4 x0 = dp4[0], x1 = dp4[1], x2 = dp4[2];
            float acc = dtb
                + x0.x*dtw[0] + x0.y*dtw[1] + x0.z*dtw[2]  + x0.w*dtw[3]
                + x1.x*dtw[4] + x1.y*dtw[5] + x1.z*dtw[6]  + x1.w*dtw[7]
                + x2.x*dtw[8] + x2.y*dtw[9] + x2.z*dtw[10] + x2.w*dtw[11];
            deltab[i] = softplus_f(acc);
            ub[i] = up[pos_for(k, lme)];
        }

#define SSTEP(J) { \
        constexpr int S_ = (J) >> 2, I_ = (J) & 3; \
        float delta = dpp_movf<S_ * 0x55>(deltab[I_]); \
        float ub_b  = dpp_movf<S_ * 0x55>(ub[I_]); \
        td += delta; \
        float du = delta * ub_b; \
        float4 B4 = *(const float4*)(Bp + (size_t)(lb + (J)) * NN + n0); \
        float dA0 = __expf(delta * A[0]); h[0] = h[0] * dA0 + du * B4.x; \
        float dA1 = __expf(delta * A[1]); h[1] = h[1] * dA1 + du * B4.y; \
        float dA2 = __expf(delta * A[2]); h[2] = h[2] * dA2 + du * B4.z; \
        float dA3 = __expf(delta * A[3]); h[3] = h[3] * dA3 + du * B4.w; \
        float4 C4 = *(const float4*)(Cp + (size_t)(lb + (J)) * NN + n0); \
        float yp = h[0]*C4.x + h[1]*C4.y + h[2]*C4.z + h[3]*C4.w; \
        yp += dpp_movf<0xB1>(yp); \
        yp += dpp_movf<0x4E>(yp); \
        float yf = yp + ub_b * Dv; \
        if (q == ((J) & 3)) { yhold = yf; Shold = td; } \
        if (((J) & 3) == 3) { \
            size_t row = (size_t)(lb + ((J) & ~3) + q) * DI + d; \
            yk_p[row] = yhold; \
            Sb_p[row] = Shold; \
        } }

        SSTEP(0)  SSTEP(1)  SSTEP(2)  SSTEP(3)
        SSTEP(4)  SSTEP(5)  SSTEP(6)  SSTEP(7)
        SSTEP(8)  SSTEP(9)  SSTEP(10) SSTEP(11)
        SSTEP(12) SSTEP(13) SSTEP(14) SSTEP(15)
#undef SSTEP
    }

    float4 h4; h4.x = h[0]; h4.y = h[1]; h4.z = h[2]; h4.w = h[3];
    *(float4*)(hstin + ((size_t)(bk * CH + c) * DI + d) * NN + n0) = h4;
}

// ---------------- combine (in-place): hstin holds chunk end-states on entry,
// chunk INCOMING states on exit.
__global__ __launch_bounds__(256) void k_scan_combine(
    float* __restrict__ hstin,
    const float* __restrict__ Sbuf,
    const float* __restrict__ Alogs)
{
    int t = blockIdx.x * 256 + threadIdx.x;   // B*K*DI*NN = 98304
    int n = t & 15;
    int d = (t >> 4) % DI;
    int bk = t / (DI * NN);
    int k = bk & 3;
    float A = -expf(Alogs[(size_t)(k * DI + d) * NN + n]);
    float h = 0.f;
    for (int c = 0; c < CH; ++c) {
        size_t rb = (size_t)(bk * CH + c) * DI + d;
        float hend = hstin[rb * NN + n];
        hstin[rb * NN + n] = h;               // incoming state for chunk c
        float St = Sbuf[((size_t)bk * LL + c * CLEN + CLEN - 1) * DI + d];
        h = __expf(A * St) * h + hend;
    }
}

// ---------------- correction: exclusive (bk,chunk,dblk) region of yk,
// plain load-add-store (no atomics).
__global__ __launch_bounds__(256) void k_corr(
    const float* __restrict__ Csb,
    const float* __restrict__ Sbuf,
    const float* __restrict__ hin,
    const float* __restrict__ Alogs,
    float* __restrict__ yk)
{
    int blk = blockIdx.x;                 // ((bk*CH + c)*6 + dblk)
    int dblk = blk % 6;
    int tmp = blk / 6;
    int c = tmp % CH;
    if (c == 0) return;                   // h_in == 0 -> zero correction
    int bk = tmp / CH;
    int k = bk & 3;
    int lane = threadIdx.x & 63, wv = threadIdx.x >> 6;
    int q = lane & 3;
    int d16 = lane >> 2;
    int d = dblk * 64 + wv * 16 + d16;
    int kd = k * DI + d;
    int n0 = q << 2;

    float4 Al = *(const float4*)(Alogs + (size_t)kd * NN + n0);
    float A[4] = { -expf(Al.x), -expf(Al.y), -expf(Al.z), -expf(Al.w) };
    float4 H4 = *(const float4*)(hin + ((size_t)(bk * CH + c) * DI + d) * NN + n0);
    const float* Cp = Csb + (size_t)bk * LL * NN;
    const float* Sp = Sbuf + (size_t)bk * LL * DI;
    float* yk_p = yk + (size_t)bk * LL * DI;

    int l0 = c * CLEN;
    float ychold = 0.f;
    for (int l = l0; l < l0 + CLEN; ++l) {
        float S = Sp[(size_t)l * DI + d];
        float4 C4 = *(const float4*)(Cp + (size_t)l * NN + n0);
        float yc = C4.x * __expf(A[0] * S) * H4.x
                 + C4.y * __expf(A[1] * S) * H4.y
                 + C4.z * __expf(A[2] * S) * H4.z
                 + C4.w * __expf(A[3] * S) * H4.w;
        yc += dpp_movf<0xB1>(yc);
        yc += dpp_movf<0x4E>(yc);
        if (q == (l & 3)) ychold = yc;
        if ((l & 3) == 3) {
            size_t row = (size_t)((l & ~3) + q) * DI + d;
            yk_p[row] += ychold;
        }
    }
}

// ---------------- merge (CrossMerge) + LayerNorm + gate, one block per (b,pos)
__global__ __launch_bounds__(384) void k_merge_ln_gate(
    const float* __restrict__ yk,
    const float* __restrict__ z1,
    const float* __restrict__ lnw,
    const float* __restrict__ lnb,
    float* __restrict__ gbuf)
{
    int pg = blockIdx.x;            // b*LL + pos
    int b = pg / LL;
    int pos = pg % LL;
    int d = threadIdx.x;
    int pt = (pos % 48) * 48 + pos / 48;

    const float* y0 = yk + ((size_t)(b * 4 + 0) * LL + pos) * DI;
    const float* y1 = yk + ((size_t)(b * 4 + 1) * LL + pt) * DI;
    const float* y2 = yk + ((size_t)(b * 4 + 2) * LL + (LL - 1 - pos)) * DI;
    const float* y3 = yk + ((size_t)(b * 4 + 3) * LL + (LL - 1 - pt)) * DI;
    float v = y0[d] + y1[d] + y2[d] + y3[d];

    float s = v, qq = v * v;
    #pragma unroll
    for (int o = 32; o >= 1; o >>= 1) {
        s += __shfl_xor(s, o, 64);
        qq += __shfl_xor(qq, o, 64);
    }
    __shared__ float ssum[6], sqq[6];
    int lane = d & 63, w = d >> 6;
    if (lane == 0) { ssum[w] = s; sqq[w] = qq; }
    __syncthreads();
    float ts = 0.f, tq = 0.f;
    #pragma unroll
    for (int i = 0; i < 6; ++i) { ts += ssum[i]; tq += sqq[i]; }
    float mu = ts / (float)DI;
    float var = tq / (float)DI - mu * mu;
    float inv = rsqrtf(var + 1e-5f);
    float y = (v - mu) * inv * lnw[d] + lnb[d];
    gbuf[(size_t)pg * DI + d] = y * z1[(size_t)pg * DI + d];
}

// ---------------- K6: out_proj 1x1 (192x384 GEMM)
__global__ __launch_bounds__(256) void k_outproj(const float* __restrict__ gbuf,
                                                 const float* __restrict__ w,
                                                 float* __restrict__ out) {
    __shared__ float xt[16 * 385];
    const int nt = LL / 16;
    int b = blockIdx.x / nt;
    int l0 = (blockIdx.x % nt) * 16;
    for (int idx = threadIdx.x; idx < DI * 16; idx += 256) {
        int d = idx % DI;
        int lt = idx / DI;
        xt[lt * 385 + d] = gbuf[(size_t)(b * LL + l0 + lt) * DI + d];
    }
    __syncthreads();
    for (int pass = 0; pass < 3; ++pass) {
        int t = pass * 256 + threadIdx.x;
        int o = t >> 2, ltq = t & 3;
        float s0 = 0.f, s1 = 0.f, s2 = 0.f, s3 = 0.f;
        const float* wr = w + (size_t)o * DI;
        int base = (ltq * 4) * 385;
        for (int d = 0; d < DI; ++d) {
            float wv = wr[d];
            s0 += wv * xt[base + d];
            s1 += wv * xt[base + 385 + d];
            s2 += wv * xt[base + 2 * 385 + d];
            s3 += wv * xt[base + 3 * 385 + d];
        }
        float* p = out + (size_t)(b * DM + o) * LL + l0 + ltq * 4;
        p[0] = s0; p[1] = s1; p[2] = s2; p[3] = s3;
    }
}

extern "C" void kernel_launch(void* const* d_in, const int* in_sizes, int n_in,
                              void* d_out, int out_size, void* d_ws, size_t ws_size,
                              hipStream_t stream) {
    (void)in_sizes; (void)n_in; (void)out_size; (void)ws_size;
    const float* x      = (const float*)d_in[0];
    const float* ipw    = (const float*)d_in[1];
    const float* cw     = (const float*)d_in[2];
    const float* cb     = (const float*)d_in[3];
    const float* xpw    = (const float*)d_in[4];
    const float* dtw    = (const float*)d_in[5];
    const float* dtb    = (const float*)d_in[6];
    const float* Alogs  = (const float*)d_in[7];
    const float* Ds     = (const float*)d_in[8];
    const float* lnw    = (const float*)d_in[9];
    const float* lnb    = (const float*)d_in[10];
    const float* opw    = (const float*)d_in[11];
    float* out = (float*)d_out;

    float* wsf = (float*)d_ws;
    const size_t SZ  = (size_t)BQ * DI * LL;              // 3,538,944
    const size_t DTS = (size_t)BQ * KK * LL * RR;         //   442,368
    const size_t BCS = (size_t)BQ * KK * LL * NN;         //   589,824
    const size_t SBF = (size_t)BQ * KK * LL * DI;         // 14,155,776
    const size_t HST = (size_t)BQ * KK * CH * DI * NN;    //  4,718,592

    float* z1      = wsf;                 // (B,L,DI)
    float* xc_pre  = z1 + SZ;             // (B,DI,L); reused as gbuf
    float* xc_conv = xc_pre + SZ;         // (B,DI,L)
    float* dts     = xc_conv + SZ;        // (B,K,L,R)
    float* Bsb     = dts + DTS;           // (B,K,L,N)
    float* Csb     = Bsb + BCS;           // (B,K,L,N)
    float* Sbuf    = Csb + BCS;           // (B,K,L,DI)
    float* hstin   = Sbuf + SBF;          // (B,K,CH,DI,N) end-states -> incoming
    float* yk      = hstin + HST;         // (B,K,L,DI) per-direction y
    float* gbuf    = xc_pre;

    k_inproj<<<BQ * (LL / 16), 256, 0, stream>>>(x, ipw, xc_pre, z1);
    k_dwconv<<<(BQ * DI * HH * (WW / 4) + 255) / 256, 256, 0, stream>>>(
        xc_pre, cw, cb, xc_conv);
    k_xproj<<<BQ * KK * (LL / 16), 256, 0, stream>>>(xc_conv, xpw, dts, Bsb, Csb);

    k_scan_pass1<<<BQ * KK * CH * 6, 256, 0, stream>>>(
        xc_conv, dts, Bsb, Csb, dtw, dtb, Alogs, Ds, Sbuf, hstin, yk);
    k_scan_combine<<<(BQ * KK * DI * NN) / 256, 256, 0, stream>>>(
        hstin, Sbuf, Alogs);
    k_corr<<<BQ * KK * CH * 6, 256, 0, stream>>>(Csb, Sbuf, hstin, Alogs, yk);
    k_merge_ln_gate<<<BQ * LL, 384, 0, stream>>>(yk, z1, lnw, lnb, gbuf);

    k_outproj<<<BQ * (LL / 16), 256, 0, stream>>>(gbuf, opw, out);
}

// Round 6
// 431.859 us; speedup vs baseline: 1.5598x; 1.3040x over previous
//
#include <hip/hip_runtime.h>
#include <math.h>

#define BQ 4
#define DM 192
#define DI 384
#define HH 48
#define WW 48
#define LL 2304
#define KK 4
#define NN 16
#define RR 12
#define CH 48      // chunks per sequence
#define CLEN 48    // chunk length
#define NBATCH 3   // CLEN/16

#define LOG2E 1.4426950408889634f

__device__ __forceinline__ float gelu_exact(float x) {
    return 0.5f * x * (1.0f + erff(x * 0.7071067811865476f));
}

__device__ __forceinline__ float softplus_f(float x) {
    return fmaxf(x, 0.0f) + log1pf(expf(-fabsf(x)));
}

__device__ __forceinline__ int pos_for(int k, int l) {
    if (k == 0) return l;
    if (k == 1) { return (l % HH) * WW + (l / HH); }
    if (k == 2) return (LL - 1) - l;
    int j = (LL - 1) - l;
    return (j % HH) * WW + (j / HH);
}

__device__ __forceinline__ float fexp2(float x) {
    return __builtin_amdgcn_exp2f(x);
}

// DPP move: 0x00-0xFF quad_perm; 0xB1 = quad xor1, 0x4E = quad xor2.
template<int CTRL>
__device__ __forceinline__ float dpp_movf(float v) {
    return __int_as_float(__builtin_amdgcn_update_dpp(
        0, __float_as_int(v), CTRL, 0xF, 0xF, true));
}

// ---------------- K1: in_proj 1x1 -> register-tiled GEMM 64x64, 4x4/thread.
// o<384 -> xc_pre[b][o][l]; o>=384 -> gelu -> z1[b][l][oz] (full-line rows).
__global__ __launch_bounds__(256) void k_inproj(const float* __restrict__ x,
                                                const float* __restrict__ w,
                                                float* __restrict__ xc_pre,
                                                float* __restrict__ z1) {
    __shared__ float As[16][68];
    __shared__ float Bs[16][68];
    int o0 = blockIdx.x * 64;
    int l0 = blockIdx.y * 64;
    int b  = blockIdx.z;
    int t = threadIdx.x;
    int tx = t & 15, ty = t >> 4;
    float acc[4][4] = {{0.f}};
    int lo_o = t >> 2, kq = (t & 3) << 2;    // W loader
    int lo_k = t >> 4, l4 = (t & 15) << 2;   // X loader
    const float* wp = w + (size_t)(o0 + lo_o) * DM + kq;
    const float* xp = x + (size_t)(b * DM + lo_k) * LL + l0 + l4;
    for (int k0 = 0; k0 < DM; k0 += 16) {
        float4 wv = *(const float4*)wp; wp += 16;
        float4 xv = *(const float4*)xp; xp += 16 * LL;
        As[kq + 0][lo_o] = wv.x; As[kq + 1][lo_o] = wv.y;
        As[kq + 2][lo_o] = wv.z; As[kq + 3][lo_o] = wv.w;
        *(float4*)&Bs[lo_k][l4] = xv;
        __syncthreads();
        #pragma unroll
        for (int k = 0; k < 16; ++k) {
            float4 a  = *(const float4*)&As[k][ty * 4];
            float4 bv = *(const float4*)&Bs[k][tx * 4];
            acc[0][0] += a.x * bv.x; acc[0][1] += a.x * bv.y;
            acc[0][2] += a.x * bv.z; acc[0][3] += a.x * bv.w;
            acc[1][0] += a.y * bv.x; acc[1][1] += a.y * bv.y;
            acc[1][2] += a.y * bv.z; acc[1][3] += a.y * bv.w;
            acc[2][0] += a.z * bv.x; acc[2][1] += a.z * bv.y;
            acc[2][2] += a.z * bv.z; acc[2][3] += a.z * bv.w;
            acc[3][0] += a.w * bv.x; acc[3][1] += a.w * bv.y;
            acc[3][2] += a.w * bv.z; acc[3][3] += a.w * bv.w;
        }
        __syncthreads();
    }
    if (o0 < DI) {
        float* base = xc_pre + (size_t)(b * DI + o0 + ty * 4) * LL + l0 + tx * 4;
        #pragma unroll
        for (int io = 0; io < 4; ++io) {
            float4 v = { acc[io][0], acc[io][1], acc[io][2], acc[io][3] };
            *(float4*)(base + (size_t)io * LL) = v;
        }
    } else {
        float* base = z1 + ((size_t)(b * LL + l0 + tx * 4)) * DI + (o0 - DI + ty * 4);
        #pragma unroll
        for (int jl = 0; jl < 4; ++jl) {
            float4 v = { gelu_exact(acc[0][jl]), gelu_exact(acc[1][jl]),
                         gelu_exact(acc[2][jl]), gelu_exact(acc[3][jl]) };
            *(float4*)(base + (size_t)jl * DI) = v;
        }
    }
}

// ---------------- K2: depthwise 3x3 conv + bias + gelu, 4 outputs/thread
__global__ __launch_bounds__(256) void k_dwconv(const float* __restrict__ xc_pre,
                                                const float* __restrict__ cw,
                                                const float* __restrict__ cb,
                                                float* __restrict__ xc_conv) {
    int idx = blockIdx.x * 256 + threadIdx.x;          // B*DI*HH*12
    if (idx >= BQ * DI * HH * (WW / 4)) return;
    int wq = idx % 12;
    int w0 = wq * 4;
    int h = (idx / 12) % HH;
    int c = (idx / (12 * HH)) % DI;
    int b = idx / (12 * HH * DI);
    const float* in = xc_pre + (size_t)(b * DI + c) * LL;
    const float* k9 = cw + c * 9;
    float bias = cb[c];
    float s0 = bias, s1 = bias, s2 = bias, s3 = bias;
    #pragma unroll
    for (int dh = -1; dh <= 1; ++dh) {
        int hh = h + dh;
        if (hh < 0 || hh >= HH) continue;
        const float* r = in + hh * WW;
        float4 a = *(const float4*)(r + w0);
        float lft = (w0 > 0) ? r[w0 - 1] : 0.f;
        float rgt = (w0 + 4 < WW) ? r[w0 + 4] : 0.f;
        float k0 = k9[(dh + 1) * 3 + 0];
        float k1 = k9[(dh + 1) * 3 + 1];
        float k2 = k9[(dh + 1) * 3 + 2];
        s0 += k0 * lft + k1 * a.x + k2 * a.y;
        s1 += k0 * a.x + k1 * a.y + k2 * a.z;
        s2 += k0 * a.y + k1 * a.z + k2 * a.w;
        s3 += k0 * a.z + k1 * a.w + k2 * rgt;
    }
    float4 o;
    o.x = gelu_exact(s0); o.y = gelu_exact(s1);
    o.z = gelu_exact(s2); o.w = gelu_exact(s3);
    *(float4*)(xc_conv + (size_t)(b * DI + c) * LL + h * WW + w0) = o;
}

// ---------------- transpose xc_conv[b][d][l] -> xcT[b][l][d], 32x32 tiles
__global__ __launch_bounds__(256) void k_transpose(const float* __restrict__ in,
                                                   float* __restrict__ outT) {
    __shared__ float T[32][33];
    int blk = blockIdx.x;           // (b*72 + lt)*12 + dt
    int dt = blk % 12;
    int lt = (blk / 12) % 72;
    int b  = blk / (12 * 72);
    int d0 = dt * 32, l0 = lt * 32;
    int tx = threadIdx.x & 31, ty = threadIdx.x >> 5;   // ty 0..7
    #pragma unroll
    for (int i = 0; i < 4; ++i) {
        int dd = ty + 8 * i;
        T[dd][tx] = in[(size_t)(b * DI + d0 + dd) * LL + l0 + tx];
    }
    __syncthreads();
    #pragma unroll
    for (int i = 0; i < 4; ++i) {
        int ll = ty + 8 * i;
        outT[(size_t)(b * LL + l0 + ll) * DI + d0 + tx] = T[tx][ll];
    }
}

// ---------------- K3: x_proj per direction (reads xcT, coalesced both sides)
__global__ __launch_bounds__(256) void k_xproj(const float* __restrict__ xcT,
                                               const float* __restrict__ xpw,
                                               float* __restrict__ dts,
                                               float* __restrict__ Bsb,
                                               float* __restrict__ Csb) {
    __shared__ float xt[16 * 385];
    const int nt = LL / 16;
    int l0 = (blockIdx.x % nt) * 16;
    int bk = blockIdx.x / nt;
    int k = bk % KK;
    int b = bk / KK;
    for (int idx = threadIdx.x; idx < DI * 16; idx += 256) {
        int d = idx % DI;
        int lt = idx / DI;
        int pos = pos_for(k, l0 + lt);
        xt[lt * 385 + d] = xcT[((size_t)b * LL + pos) * DI + d];
    }
    __syncthreads();
    int t = threadIdx.x;
    if (t < 176) {
        int c = t >> 2, ltq = t & 3;
        float s0 = 0.f, s1 = 0.f, s2 = 0.f, s3 = 0.f;
        const float* wr = xpw + (size_t)(k * 44 + c) * DI;
        int base = (ltq * 4) * 385;
        for (int d = 0; d < DI; ++d) {
            float wv = wr[d];
            s0 += wv * xt[base + d];
            s1 += wv * xt[base + 385 + d];
            s2 += wv * xt[base + 2 * 385 + d];
            s3 += wv * xt[base + 3 * 385 + d];
        }
        float sv[4] = {s0, s1, s2, s3};
        #pragma unroll
        for (int j = 0; j < 4; ++j) {
            int l = l0 + ltq * 4 + j;
            if (c < RR)
                dts[((size_t)bk * LL + l) * RR + c] = sv[j];
            else if (c < RR + NN)
                Bsb[((size_t)bk * LL + l) * NN + (c - RR)] = sv[j];
            else
                Csb[((size_t)bk * LL + l) * NN + (c - RR - NN)] = sv[j];
        }
    }
}

// ---------------- Single-pass chunked scan (h from 0). Pointer-bumped,
// exp2-folded decay, u from xcT (coalesced row segments). No atomics.
__global__ __launch_bounds__(256) void k_scan_pass1(
    const float* __restrict__ xcT,
    const float* __restrict__ dts,
    const float* __restrict__ Bsb,
    const float* __restrict__ Csb,
    const float* __restrict__ dtw_g,
    const float* __restrict__ dtb_g,
    const float* __restrict__ Alogs,
    const float* __restrict__ Ds_g,
    float* __restrict__ Sbuf,
    float* __restrict__ hstin,
    float* __restrict__ yk)
{
    int blk = blockIdx.x;                 // ((bk*CH + c)*6 + dblk)
    int dblk = blk % 6;
    int tmp = blk / 6;
    int c = tmp % CH;
    int bk = tmp / CH;
    int k = bk & 3, b = bk >> 2;
    int tid = threadIdx.x;
    int lane = tid & 63, wv = tid >> 6;
    int q = lane & 3;
    int d16 = lane >> 2;
    int d = dblk * 64 + wv * 16 + d16;
    int kd = k * DI + d;
    int n0 = q << 2;

    float4 Al = *(const float4*)(Alogs + (size_t)kd * NN + n0);
    float A2[4] = { -expf(Al.x) * LOG2E, -expf(Al.y) * LOG2E,
                    -expf(Al.z) * LOG2E, -expf(Al.w) * LOG2E };
    float dtb = dtb_g[kd];
    float dtw[12];
    {
        const float4* p = (const float4*)(dtw_g + (size_t)kd * RR);
        float4 a0 = p[0], a1 = p[1], a2 = p[2];
        dtw[0]=a0.x; dtw[1]=a0.y; dtw[2]=a0.z;  dtw[3]=a0.w;
        dtw[4]=a1.x; dtw[5]=a1.y; dtw[6]=a1.z;  dtw[7]=a1.w;
        dtw[8]=a2.x; dtw[9]=a2.y; dtw[10]=a2.z; dtw[11]=a2.w;
    }
    int l0 = c * CLEN;
    const float* dt_lane = dts + ((size_t)bk * LL + l0 + n0) * RR;
    const float* Bc = Bsb + ((size_t)bk * LL + l0) * NN + n0;
    const float* Cc = Csb + ((size_t)bk * LL + l0) * NN + n0;
    float* Sc = Sbuf + ((size_t)bk * LL + l0 + q) * DI + d;
    float* yc = yk   + ((size_t)bk * LL + l0 + q) * DI + d;
    const float* xT_b = xcT + (size_t)b * LL * DI + d;

    float h0 = 0.f, h1 = 0.f, h2 = 0.f, h3 = 0.f;
    float Dv = Ds_g[kd];
    float td = 0.f;
    float yhold = 0.f, Shold = 0.f;

    for (int g = 0; g < NBATCH; ++g) {
        int lb = l0 + g * 16;
        float deltab[4], ub[4];
        #pragma unroll
        for (int i = 0; i < 4; ++i) {
            const float* dp = dt_lane + i * RR;
            float4 x0 = *(const float4*)dp;
            float4 x1 = *(const float4*)(dp + 4);
            float4 x2 = *(const float4*)(dp + 8);
            float acc = dtb
                + x0.x*dtw[0] + x0.y*dtw[1] + x0.z*dtw[2]  + x0.w*dtw[3]
                + x1.x*dtw[4] + x1.y*dtw[5] + x1.z*dtw[6]  + x1.w*dtw[7]
                + x2.x*dtw[8] + x2.y*dtw[9] + x2.z*dtw[10] + x2.w*dtw[11];
            deltab[i] = softplus_f(acc);
            ub[i] = xT_b[(size_t)pos_for(k, lb + n0 + i) * DI];
        }
        dt_lane += 16 * RR;

#define SSTEP(J) { \
        constexpr int S_ = (J) >> 2, I_ = (J) & 3; \
        float delta = dpp_movf<S_ * 0x55>(deltab[I_]); \
        float ub_b  = dpp_movf<S_ * 0x55>(ub[I_]); \
        td += delta; \
        float du = delta * ub_b; \
        float4 B4 = *(const float4*)(Bc + (J) * NN); \
        h0 = h0 * fexp2(delta * A2[0]) + du * B4.x; \
        h1 = h1 * fexp2(delta * A2[1]) + du * B4.y; \
        h2 = h2 * fexp2(delta * A2[2]) + du * B4.z; \
        h3 = h3 * fexp2(delta * A2[3]) + du * B4.w; \
        float4 C4 = *(const float4*)(Cc + (J) * NN); \
        float yp = h0*C4.x + h1*C4.y + h2*C4.z + h3*C4.w; \
        yp += dpp_movf<0xB1>(yp); \
        yp += dpp_movf<0x4E>(yp); \
        float yf = yp + ub_b * Dv; \
        if (q == ((J) & 3)) { yhold = yf; Shold = td; } \
        if (((J) & 3) == 3) { *yc = yhold; *Sc = Shold; yc += 4 * DI; Sc += 4 * DI; } }

        SSTEP(0)  SSTEP(1)  SSTEP(2)  SSTEP(3)
        SSTEP(4)  SSTEP(5)  SSTEP(6)  SSTEP(7)
        SSTEP(8)  SSTEP(9)  SSTEP(10) SSTEP(11)
        SSTEP(12) SSTEP(13) SSTEP(14) SSTEP(15)
#undef SSTEP
        Bc += 16 * NN;
        Cc += 16 * NN;
    }

    float4 h4; h4.x = h0; h4.y = h1; h4.z = h2; h4.w = h3;
    *(float4*)(hstin + ((size_t)(bk * CH + c) * DI + d) * NN + n0) = h4;
}

// ---------------- combine (in-place): end-states -> incoming states
__global__ __launch_bounds__(256) void k_scan_combine(
    float* __restrict__ hstin,
    const float* __restrict__ Sbuf,
    const float* __restrict__ Alogs)
{
    int t = blockIdx.x * 256 + threadIdx.x;   // B*K*DI*NN = 98304
    int n = t & 15;
    int d = (t >> 4) % DI;
    int bk = t / (DI * NN);
    int k = bk & 3;
    float A2 = -expf(Alogs[(size_t)(k * DI + d) * NN + n]) * LOG2E;
    float h = 0.f;
    for (int c = 0; c < CH; ++c) {
        size_t rb = (size_t)(bk * CH + c) * DI + d;
        float hend = hstin[rb * NN + n];
        hstin[rb * NN + n] = h;
        float St = Sbuf[((size_t)bk * LL + c * CLEN + CLEN - 1) * DI + d];
        h = fexp2(A2 * St) * h + hend;
    }
}

// ---------------- correction: pointer-bumped, plain RMW on exclusive region
__global__ __launch_bounds__(256) void k_corr(
    const float* __restrict__ Csb,
    const float* __restrict__ Sbuf,
    const float* __restrict__ hin,
    const float* __restrict__ Alogs,
    float* __restrict__ yk)
{
    int blk = blockIdx.x;                 // ((bk*CH + c)*6 + dblk)
    int dblk = blk % 6;
    int tmp = blk / 6;
    int c = tmp % CH;
    if (c == 0) return;
    int bk = tmp / CH;
    int k = bk & 3;
    int lane = threadIdx.x & 63, wv = threadIdx.x >> 6;
    int q = lane & 3;
    int d16 = lane >> 2;
    int d = dblk * 64 + wv * 16 + d16;
    int kd = k * DI + d;
    int n0 = q << 2;

    float4 Al = *(const float4*)(Alogs + (size_t)kd * NN + n0);
    float A2[4] = { -expf(Al.x) * LOG2E, -expf(Al.y) * LOG2E,
                    -expf(Al.z) * LOG2E, -expf(Al.w) * LOG2E };
    float4 H4 = *(const float4*)(hin + ((size_t)(bk * CH + c) * DI + d) * NN + n0);
    int l0 = c * CLEN;
    const float* Cc = Csb + ((size_t)bk * LL + l0) * NN + n0;
    const float* Sc = Sbuf + ((size_t)bk * LL + l0) * DI + d;
    float* yc = yk + ((size_t)bk * LL + l0 + q) * DI + d;

    for (int lg = 0; lg < CLEN; lg += 4) {
        float ychold = 0.f;
        #pragma unroll
        for (int j = 0; j < 4; ++j) {
            float S = Sc[(size_t)j * DI];
            float4 C4 = *(const float4*)(Cc + j * NN);
            float yv = C4.x * fexp2(A2[0] * S) * H4.x
                     + C4.y * fexp2(A2[1] * S) * H4.y
                     + C4.z * fexp2(A2[2] * S) * H4.z
                     + C4.w * fexp2(A2[3] * S) * H4.w;
            yv += dpp_movf<0xB1>(yv);
            yv += dpp_movf<0x4E>(yv);
            if (q == j) ychold = yv;
        }
        Sc += 4 * DI;
        Cc += 4 * NN;
        *yc += ychold;
        yc += 4 * DI;
    }
}

// ---------------- merge (CrossMerge) + LayerNorm + gate, one block per (b,pos)
__global__ __launch_bounds__(384) void k_merge_ln_gate(
    const float* __restrict__ yk,
    const float* __restrict__ z1,
    const float* __restrict__ lnw,
    const float* __restrict__ lnb,
    float* __restrict__ gbuf)
{
    int pg = blockIdx.x;            // b*LL + pos
    int b = pg / LL;
    int pos = pg % LL;
    int d = threadIdx.x;
    int pt = (pos % 48) * 48 + pos / 48;

    const float* y0 = yk + ((size_t)(b * 4 + 0) * LL + pos) * DI;
    const float* y1 = yk + ((size_t)(b * 4 + 1) * LL + pt) * DI;
    const float* y2 = yk + ((size_t)(b * 4 + 2) * LL + (LL - 1 - pos)) * DI;
    const float* y3 = yk + ((size_t)(b * 4 + 3) * LL + (LL - 1 - pt)) * DI;
    float v = y0[d] + y1[d] + y2[d] + y3[d];

    float s = v, qq = v * v;
    #pragma unroll
    for (int o = 32; o >= 1; o >>= 1) {
        s += __shfl_xor(s, o, 64);
        qq += __shfl_xor(qq, o, 64);
    }
    __shared__ float ssum[6], sqq[6];
    int lane = d & 63, w = d >> 6;
    if (lane == 0) { ssum[w] = s; sqq[w] = qq; }
    __syncthreads();
    float ts = 0.f, tq = 0.f;
    #pragma unroll
    for (int i = 0; i < 6; ++i) { ts += ssum[i]; tq += sqq[i]; }
    float mu = ts / (float)DI;
    float var = tq / (float)DI - mu * mu;
    float inv = rsqrtf(var + 1e-5f);
    float y = (v - mu) * inv * lnw[d] + lnb[d];
    gbuf[(size_t)pg * DI + d] = y * z1[(size_t)pg * DI + d];
}

// ---------------- K6: out_proj -> register-tiled GEMM 64x64 (K=DI)
__global__ __launch_bounds__(256) void k_outproj(const float* __restrict__ gbuf,
                                                 const float* __restrict__ w,
                                                 float* __restrict__ out) {
    __shared__ float As[16][68];
    __shared__ float Bs[16][68];
    int o0 = blockIdx.x * 64;
    int l0 = blockIdx.y * 64;
    int b  = blockIdx.z;
    int t = threadIdx.x;
    int tx = t & 15, ty = t >> 4;
    float acc[4][4] = {{0.f}};
    int lo_o = t >> 2, kq = (t & 3) << 2;    // W loader
    int lo_l = t >> 2, d4 = (t & 3) << 2;    // G loader
    const float* wp = w + (size_t)(o0 + lo_o) * DI + kq;
    const float* gp = gbuf + ((size_t)(b * LL + l0 + lo_l)) * DI + d4;
    for (int k0 = 0; k0 < DI; k0 += 16) {
        float4 wv = *(const float4*)wp; wp += 16;
        float4 gv = *(const float4*)gp; gp += 16;
        As[kq + 0][lo_o] = wv.x; As[kq + 1][lo_o] = wv.y;
        As[kq + 2][lo_o] = wv.z; As[kq + 3][lo_o] = wv.w;
        Bs[d4 + 0][lo_l] = gv.x; Bs[d4 + 1][lo_l] = gv.y;
        Bs[d4 + 2][lo_l] = gv.z; Bs[d4 + 3][lo_l] = gv.w;
        __syncthreads();
        #pragma unroll
        for (int k = 0; k < 16; ++k) {
            float4 a  = *(const float4*)&As[k][ty * 4];
            float4 bv = *(const float4*)&Bs[k][tx * 4];
            acc[0][0] += a.x * bv.x; acc[0][1] += a.x * bv.y;
            acc[0][2] += a.x * bv.z; acc[0][3] += a.x * bv.w;
            acc[1][0] += a.y * bv.x; acc[1][1] += a.y * bv.y;
            acc[1][2] += a.y * bv.z; acc[1][3] += a.y * bv.w;
            acc[2][0] += a.z * bv.x; acc[2][1] += a.z * bv.y;
            acc[2][2] += a.z * bv.z; acc[2][3] += a.z * bv.w;
            acc[3][0] += a.w * bv.x; acc[3][1] += a.w * bv.y;
            acc[3][2] += a.w * bv.z; acc[3][3] += a.w * bv.w;
        }
        __syncthreads();
    }
    float* base = out + (size_t)(b * DM + o0 + ty * 4) * LL + l0 + tx * 4;
    #pragma unroll
    for (int io = 0; io < 4; ++io) {
        float4 v = { acc[io][0], acc[io][1], acc[io][2], acc[io][3] };
        *(float4*)(base + (size_t)io * LL) = v;
    }
}

extern "C" void kernel_launch(void* const* d_in, const int* in_sizes, int n_in,
                              void* d_out, int out_size, void* d_ws, size_t ws_size,
                              hipStream_t stream) {
    (void)in_sizes; (void)n_in; (void)out_size; (void)ws_size;
    const float* x      = (const float*)d_in[0];
    const float* ipw    = (const float*)d_in[1];
    const float* cw     = (const float*)d_in[2];
    const float* cb     = (const float*)d_in[3];
    const float* xpw    = (const float*)d_in[4];
    const float* dtw    = (const float*)d_in[5];
    const float* dtb    = (const float*)d_in[6];
    const float* Alogs  = (const float*)d_in[7];
    const float* Ds     = (const float*)d_in[8];
    const float* lnw    = (const float*)d_in[9];
    const float* lnb    = (const float*)d_in[10];
    const float* opw    = (const float*)d_in[11];
    float* out = (float*)d_out;

    float* wsf = (float*)d_ws;
    const size_t SZ  = (size_t)BQ * DI * LL;              // 3,538,944
    const size_t DTS = (size_t)BQ * KK * LL * RR;
    const size_t BCS = (size_t)BQ * KK * LL * NN;
    const size_t SBF = (size_t)BQ * KK * LL * DI;         // 14,155,776
    const size_t HST = (size_t)BQ * KK * CH * DI * NN;    //  4,718,592

    float* z1      = wsf;                 // (B,L,DI)
    float* bufA    = z1 + SZ;             // xc_pre, then xcT
    float* bufB    = bufA + SZ;           // xc_conv, then gbuf
    float* dts     = bufB + SZ;           // (B,K,L,R)
    float* Bsb     = dts + DTS;           // (B,K,L,N)
    float* Csb     = Bsb + BCS;           // (B,K,L,N)
    float* Sbuf    = Csb + BCS;           // (B,K,L,DI)
    float* hstin   = Sbuf + SBF;          // (B,K,CH,DI,N)
    float* yk      = hstin + HST;         // (B,K,L,DI)

    float* xc_pre  = bufA;
    float* xc_conv = bufB;
    float* xcT     = bufA;                // overwrites xc_pre (dead after dwconv)
    float* gbuf    = bufB;                // overwrites xc_conv (dead after transpose+scan staging)

    k_inproj<<<dim3(12, 36, BQ), 256, 0, stream>>>(x, ipw, xc_pre, z1);
    k_dwconv<<<(BQ * DI * HH * (WW / 4) + 255) / 256, 256, 0, stream>>>(
        xc_pre, cw, cb, xc_conv);
    k_transpose<<<BQ * 72 * 12, 256, 0, stream>>>(xc_conv, xcT);
    k_xproj<<<BQ * KK * (LL / 16), 256, 0, stream>>>(xcT, xpw, dts, Bsb, Csb);

    k_scan_pass1<<<BQ * KK * CH * 6, 256, 0, stream>>>(
        xcT, dts, Bsb, Csb, dtw, dtb, Alogs, Ds, Sbuf, hstin, yk);
    k_scan_combine<<<(BQ * KK * DI * NN) / 256, 256, 0, stream>>>(
        hstin, Sbuf, Alogs);
    k_corr<<<BQ * KK * CH * 6, 256, 0, stream>>>(Csb, Sbuf, hstin, Alogs, yk);
    k_merge_ln_gate<<<BQ * LL, 384, 0, stream>>>(yk, z1, lnw, lnb, gbuf);

    k_outproj<<<dim3(3, 36, BQ), 256, 0, stream>>>(gbuf, opw, out);
}

// Round 8
// 393.209 us; speedup vs baseline: 1.7131x; 1.0983x over previous
//
#include <hip/hip_runtime.h>
#include <math.h>

#define BQ 4
#define DM 192
#define DI 384
#define HH 48
#define WW 48
#define LL 2304
#define KK 4
#define NN 16
#define RR 12
#define CH 48      // chunks per sequence
#define CLEN 48    // chunk length

#define LOG2E 1.4426950408889634f

__device__ __forceinline__ float gelu_exact(float x) {
    return 0.5f * x * (1.0f + erff(x * 0.7071067811865476f));
}

__device__ __forceinline__ float softplus_f(float x) {
    return fmaxf(x, 0.0f) + log1pf(expf(-fabsf(x)));
}

__device__ __forceinline__ int pos_for(int k, int l) {
    if (k == 0) return l;
    if (k == 1) { return (l % HH) * WW + (l / HH); }
    if (k == 2) return (LL - 1) - l;
    int j = (LL - 1) - l;
    return (j % HH) * WW + (j / HH);
}

__device__ __forceinline__ float fexp2(float x) {
    return __builtin_amdgcn_exp2f(x);
}

// DPP move: 0x00-0xFF quad_perm; 0xB1 = quad xor1, 0x4E = quad xor2.
template<int CTRL>
__device__ __forceinline__ float dpp_movf(float v) {
    return __int_as_float(__builtin_amdgcn_update_dpp(
        0, __float_as_int(v), CTRL, 0xF, 0xF, true));
}

// ---------------- K1: in_proj 1x1 -> register-tiled GEMM 64x64, 4x4/thread.
__global__ __launch_bounds__(256) void k_inproj(const float* __restrict__ x,
                                                const float* __restrict__ w,
                                                float* __restrict__ xc_pre,
                                                float* __restrict__ z1) {
    __shared__ float As[16][68];
    __shared__ float Bs[16][68];
    int o0 = blockIdx.x * 64;
    int l0 = blockIdx.y * 64;
    int b  = blockIdx.z;
    int t = threadIdx.x;
    int tx = t & 15, ty = t >> 4;
    float acc[4][4] = {{0.f}};
    int lo_o = t >> 2, kq = (t & 3) << 2;    // W loader
    int lo_k = t >> 4, l4 = (t & 15) << 2;   // X loader
    const float* wp = w + (size_t)(o0 + lo_o) * DM + kq;
    const float* xp = x + (size_t)(b * DM + lo_k) * LL + l0 + l4;
    for (int k0 = 0; k0 < DM; k0 += 16) {
        float4 wv = *(const float4*)wp; wp += 16;
        float4 xv = *(const float4*)xp; xp += 16 * LL;
        As[kq + 0][lo_o] = wv.x; As[kq + 1][lo_o] = wv.y;
        As[kq + 2][lo_o] = wv.z; As[kq + 3][lo_o] = wv.w;
        *(float4*)&Bs[lo_k][l4] = xv;
        __syncthreads();
        #pragma unroll
        for (int k = 0; k < 16; ++k) {
            float4 a  = *(const float4*)&As[k][ty * 4];
            float4 bv = *(const float4*)&Bs[k][tx * 4];
            acc[0][0] += a.x * bv.x; acc[0][1] += a.x * bv.y;
            acc[0][2] += a.x * bv.z; acc[0][3] += a.x * bv.w;
            acc[1][0] += a.y * bv.x; acc[1][1] += a.y * bv.y;
            acc[1][2] += a.y * bv.z; acc[1][3] += a.y * bv.w;
            acc[2][0] += a.z * bv.x; acc[2][1] += a.z * bv.y;
            acc[2][2] += a.z * bv.z; acc[2][3] += a.z * bv.w;
            acc[3][0] += a.w * bv.x; acc[3][1] += a.w * bv.y;
            acc[3][2] += a.w * bv.z; acc[3][3] += a.w * bv.w;
        }
        __syncthreads();
    }
    if (o0 < DI) {
        float* base = xc_pre + (size_t)(b * DI + o0 + ty * 4) * LL + l0 + tx * 4;
        #pragma unroll
        for (int io = 0; io < 4; ++io) {
            float4 v = { acc[io][0], acc[io][1], acc[io][2], acc[io][3] };
            *(float4*)(base + (size_t)io * LL) = v;
        }
    } else {
        float* base = z1 + ((size_t)(b * LL + l0 + tx * 4)) * DI + (o0 - DI + ty * 4);
        #pragma unroll
        for (int jl = 0; jl < 4; ++jl) {
            float4 v = { gelu_exact(acc[0][jl]), gelu_exact(acc[1][jl]),
                         gelu_exact(acc[2][jl]), gelu_exact(acc[3][jl]) };
            *(float4*)(base + (size_t)jl * DI) = v;
        }
    }
}

// ---------------- K2: depthwise 3x3 conv + bias + gelu, 4 outputs/thread
__global__ __launch_bounds__(256) void k_dwconv(const float* __restrict__ xc_pre,
                                                const float* __restrict__ cw,
                                                const float* __restrict__ cb,
                                                float* __restrict__ xc_conv) {
    int idx = blockIdx.x * 256 + threadIdx.x;          // B*DI*HH*12
    if (idx >= BQ * DI * HH * (WW / 4)) return;
    int wq = idx % 12;
    int w0 = wq * 4;
    int h = (idx / 12) % HH;
    int c = (idx / (12 * HH)) % DI;
    int b = idx / (12 * HH * DI);
    const float* in = xc_pre + (size_t)(b * DI + c) * LL;
    const float* k9 = cw + c * 9;
    float bias = cb[c];
    float s0 = bias, s1 = bias, s2 = bias, s3 = bias;
    #pragma unroll
    for (int dh = -1; dh <= 1; ++dh) {
        int hh = h + dh;
        if (hh < 0 || hh >= HH) continue;
        const float* r = in + hh * WW;
        float4 a = *(const float4*)(r + w0);
        float lft = (w0 > 0) ? r[w0 - 1] : 0.f;
        float rgt = (w0 + 4 < WW) ? r[w0 + 4] : 0.f;
        float k0 = k9[(dh + 1) * 3 + 0];
        float k1 = k9[(dh + 1) * 3 + 1];
        float k2 = k9[(dh + 1) * 3 + 2];
        s0 += k0 * lft + k1 * a.x + k2 * a.y;
        s1 += k0 * a.x + k1 * a.y + k2 * a.z;
        s2 += k0 * a.y + k1 * a.z + k2 * a.w;
        s3 += k0 * a.z + k1 * a.w + k2 * rgt;
    }
    float4 o;
    o.x = gelu_exact(s0); o.y = gelu_exact(s1);
    o.z = gelu_exact(s2); o.w = gelu_exact(s3);
    *(float4*)(xc_conv + (size_t)(b * DI + c) * LL + h * WW + w0) = o;
}

// ---------------- transpose xc_conv[b][d][l] -> xcT[b][l][d], 32x32 tiles
__global__ __launch_bounds__(256) void k_transpose(const float* __restrict__ in,
                                                   float* __restrict__ outT) {
    __shared__ float T[32][33];
    int blk = blockIdx.x;           // (b*72 + lt)*12 + dt
    int dt = blk % 12;
    int lt = (blk / 12) % 72;
    int b  = blk / (12 * 72);
    int d0 = dt * 32, l0 = lt * 32;
    int tx = threadIdx.x & 31, ty = threadIdx.x >> 5;   // ty 0..7
    #pragma unroll
    for (int i = 0; i < 4; ++i) {
        int dd = ty + 8 * i;
        T[dd][tx] = in[(size_t)(b * DI + d0 + dd) * LL + l0 + tx];
    }
    __syncthreads();
    #pragma unroll
    for (int i = 0; i < 4; ++i) {
        int ll = ty + 8 * i;
        outT[(size_t)(b * LL + l0 + ll) * DI + d0 + tx] = T[tx][ll];
    }
}

// ---------------- K3: x_proj per direction (reads xcT, coalesced both sides)
__global__ __launch_bounds__(256) void k_xproj(const float* __restrict__ xcT,
                                               const float* __restrict__ xpw,
                                               float* __restrict__ dts,
                                               float* __restrict__ Bsb,
                                               float* __restrict__ Csb) {
    __shared__ float xt[16 * 385];
    const int nt = LL / 16;
    int l0 = (blockIdx.x % nt) * 16;
    int bk = blockIdx.x / nt;
    int k = bk % KK;
    int b = bk / KK;
    for (int idx = threadIdx.x; idx < DI * 16; idx += 256) {
        int d = idx % DI;
        int lt = idx / DI;
        int pos = pos_for(k, l0 + lt);
        xt[lt * 385 + d] = xcT[((size_t)b * LL + pos) * DI + d];
    }
    __syncthreads();
    int t = threadIdx.x;
    if (t < 176) {
        int c = t >> 2, ltq = t & 3;
        float s0 = 0.f, s1 = 0.f, s2 = 0.f, s3 = 0.f;
        const float* wr = xpw + (size_t)(k * 44 + c) * DI;
        int base = (ltq * 4) * 385;
        for (int d = 0; d < DI; ++d) {
            float wv = wr[d];
            s0 += wv * xt[base + d];
            s1 += wv * xt[base + 385 + d];
            s2 += wv * xt[base + 2 * 385 + d];
            s3 += wv * xt[base + 3 * 385 + d];
        }
        float sv[4] = {s0, s1, s2, s3};
        #pragma unroll
        for (int j = 0; j < 4; ++j) {
            int l = l0 + ltq * 4 + j;
            if (c < RR)
                dts[((size_t)bk * LL + l) * RR + c] = sv[j];
            else if (c < RR + NN)
                Bsb[((size_t)bk * LL + l) * NN + (c - RR)] = sv[j];
            else
                Csb[((size_t)bk * LL + l) * NN + (c - RR - NN)] = sv[j];
        }
    }
}

// ---------------- Single-pass chunked scan, stage-then-scan.
// Staging: B,C,dts chunk streams + u gather + delta precompute -> LDS.
// Serial loop: pure VALU + immediate-offset LDS reads; no DPP broadcasts.
__global__ __launch_bounds__(256) void k_scan_pass1(
    const float* __restrict__ xcT,
    const float* __restrict__ dts,
    const float* __restrict__ Bsb,
    const float* __restrict__ Csb,
    const float* __restrict__ dtw_g,
    const float* __restrict__ dtb_g,
    const float* __restrict__ Alogs,
    const float* __restrict__ Ds_g,
    float* __restrict__ Sbuf,
    float* __restrict__ hstin,
    float* __restrict__ yk)
{
    __shared__ float sB[CLEN * 16];      // [l][n]
    __shared__ float sC[CLEN * 16];
    __shared__ float sDts[CLEN * 12];    // [l][r]
    __shared__ float sDel[CLEN * 64];    // [l][dl]
    __shared__ float sU[CLEN * 64];      // [l][dl]

    int blk = blockIdx.x;                 // ((bk*CH + c)*6 + dblk)
    int dblk = blk % 6;
    int tmp = blk / 6;
    int c = tmp % CH;
    int bk = tmp / CH;
    int k = bk & 3, b = bk >> 2;
    int tid = threadIdx.x;
    int l0 = c * CLEN;

    // ---- stage B, C (192 float4 each), dts (144 float4 — FULL strided loop)
    {
        const float4* Bg = (const float4*)(Bsb + ((size_t)bk * LL + l0) * NN);
        const float4* Cg = (const float4*)(Csb + ((size_t)bk * LL + l0) * NN);
        if (tid < CLEN * 4) {
            ((float4*)sB)[tid] = Bg[tid];
            ((float4*)sC)[tid] = Cg[tid];
        }
        const float4* Dg = (const float4*)(dts + ((size_t)bk * LL + l0) * RR);
        for (int i = tid; i < CLEN * 3; i += 256)
            ((float4*)sDts)[i] = Dg[i];
    }
    // ---- stage u (64-d row segments, gathered by pos_for)
    {
        const float* xb = xcT + (size_t)b * LL * DI + dblk * 64;
        #pragma unroll
        for (int it = 0; it < 3; ++it) {
            int i = it * 256 + tid;       // 768 float4
            int l = i >> 4, f4 = i & 15;
            int pos = pos_for(k, l0 + l);
            ((float4*)sU)[l * 16 + f4] = *(const float4*)(xb + (size_t)pos * DI + f4 * 4);
        }
    }
    __syncthreads();
    // ---- delta precompute: thread (lset,dl) does 12 l's for channel dl
    {
        int dl = tid & 63, lset = tid >> 6;
        int dd = dblk * 64 + dl;
        int kdq = k * DI + dd;
        float dtbv = dtb_g[kdq];
        float w12[12];
        {
            const float4* p = (const float4*)(dtw_g + (size_t)kdq * RR);
            float4 a0 = p[0], a1 = p[1], a2 = p[2];
            w12[0]=a0.x; w12[1]=a0.y; w12[2]=a0.z;  w12[3]=a0.w;
            w12[4]=a1.x; w12[5]=a1.y; w12[6]=a1.z;  w12[7]=a1.w;
            w12[8]=a2.x; w12[9]=a2.y; w12[10]=a2.z; w12[11]=a2.w;
        }
        #pragma unroll
        for (int j = 0; j < 12; ++j) {
            int l = lset * 12 + j;
            const float* dp = sDts + l * 12;
            float acc = dtbv;
            #pragma unroll
            for (int r = 0; r < 12; ++r) acc += dp[r] * w12[r];
            sDel[l * 64 + dl] = softplus_f(acc);
        }
    }
    __syncthreads();

    // ---- serial scan
    int lane = tid & 63, wv = tid >> 6;
    int q = lane & 3;
    int d16 = lane >> 2;
    int dl = wv * 16 + d16;
    int d = dblk * 64 + dl;
    int kd = k * DI + d;
    int n0 = q << 2;

    float4 Al = *(const float4*)(Alogs + (size_t)kd * NN + n0);
    float A2[4] = { -expf(Al.x) * LOG2E, -expf(Al.y) * LOG2E,
                    -expf(Al.z) * LOG2E, -expf(Al.w) * LOG2E };
    float Dv = Ds_g[kd];
    float* Sc = Sbuf + ((size_t)bk * LL + l0 + q) * DI + d;
    float* yc = yk   + ((size_t)bk * LL + l0 + q) * DI + d;

    float h0 = 0.f, h1 = 0.f, h2 = 0.f, h3 = 0.f;
    float td = 0.f;
    float yhold = 0.f, Shold = 0.f;

    #pragma unroll
    for (int l = 0; l < CLEN; ++l) {
        float delta = sDel[l * 64 + dl];
        float ub_b  = sU[l * 64 + dl];
        td += delta;
        float du = delta * ub_b;
        float4 B4 = *(const float4*)&sB[l * 16 + n0];
        h0 = h0 * fexp2(delta * A2[0]) + du * B4.x;
        h1 = h1 * fexp2(delta * A2[1]) + du * B4.y;
        h2 = h2 * fexp2(delta * A2[2]) + du * B4.z;
        h3 = h3 * fexp2(delta * A2[3]) + du * B4.w;
        float4 C4 = *(const float4*)&sC[l * 16 + n0];
        float yp = h0 * C4.x + h1 * C4.y + h2 * C4.z + h3 * C4.w;
        yp += dpp_movf<0xB1>(yp);
        yp += dpp_movf<0x4E>(yp);
        float yf = yp + ub_b * Dv;
        if (q == (l & 3)) { yhold = yf; Shold = td; }
        if ((l & 3) == 3) {
            *yc = yhold; *Sc = Shold;
            yc += 4 * DI; Sc += 4 * DI;
        }
    }

    float4 h4; h4.x = h0; h4.y = h1; h4.z = h2; h4.w = h3;
    *(float4*)(hstin + ((size_t)(bk * CH + c) * DI + d) * NN + n0) = h4;
}

// ---------------- combine (in-place): end-states -> incoming states
__global__ __launch_bounds__(256) void k_scan_combine(
    float* __restrict__ hstin,
    const float* __restrict__ Sbuf,
    const float* __restrict__ Alogs)
{
    int t = blockIdx.x * 256 + threadIdx.x;   // B*K*DI*NN = 98304
    int n = t & 15;
    int d = (t >> 4) % DI;
    int bk = t / (DI * NN);
    int k = bk & 3;
    float A2 = -expf(Alogs[(size_t)(k * DI + d) * NN + n]) * LOG2E;
    float h = 0.f;
    for (int c = 0; c < CH; ++c) {
        size_t rb = (size_t)(bk * CH + c) * DI + d;
        float hend = hstin[rb * NN + n];
        hstin[rb * NN + n] = h;
        float St = Sbuf[((size_t)bk * LL + c * CLEN + CLEN - 1) * DI + d];
        h = fexp2(A2 * St) * h + hend;
    }
}

// ---------------- correction: stage C,S in LDS, plain RMW on exclusive region
__global__ __launch_bounds__(256) void k_corr(
    const float* __restrict__ Csb,
    const float* __restrict__ Sbuf,
    const float* __restrict__ hin,
    const float* __restrict__ Alogs,
    float* __restrict__ yk)
{
    __shared__ float sC[CLEN * 16];      // [l][n]
    __shared__ float sS[CLEN * 64];      // [l][dl]

    int blk = blockIdx.x;                 // ((bk*CH + c)*6 + dblk)
    int dblk = blk % 6;
    int tmp = blk / 6;
    int c = tmp % CH;
    if (c == 0) return;
    int bk = tmp / CH;
    int k = bk & 3;
    int tid = threadIdx.x;
    int l0 = c * CLEN;

    {
        const float4* Cg = (const float4*)(Csb + ((size_t)bk * LL + l0) * NN);
        if (tid < CLEN * 4) ((float4*)sC)[tid] = Cg[tid];
        const float* Sg = Sbuf + ((size_t)bk * LL + l0) * DI + dblk * 64;
        #pragma unroll
        for (int it = 0; it < 3; ++it) {
            int i = it * 256 + tid;       // 768 float4
            int l = i >> 4, f4 = i & 15;
            ((float4*)sS)[l * 16 + f4] = *(const float4*)(Sg + (size_t)l * DI + f4 * 4);
        }
    }
    __syncthreads();

    int lane = tid & 63, wv = tid >> 6;
    int q = lane & 3;
    int d16 = lane >> 2;
    int dl = wv * 16 + d16;
    int d = dblk * 64 + dl;
    int kd = k * DI + d;
    int n0 = q << 2;

    float4 Al = *(const float4*)(Alogs + (size_t)kd * NN + n0);
    float A2[4] = { -expf(Al.x) * LOG2E, -expf(Al.y) * LOG2E,
                    -expf(Al.z) * LOG2E, -expf(Al.w) * LOG2E };
    float4 H4 = *(const float4*)(hin + ((size_t)(bk * CH + c) * DI + d) * NN + n0);
    float* yc = yk + ((size_t)bk * LL + l0 + q) * DI + d;

    float ychold = 0.f;
    #pragma unroll
    for (int l = 0; l < CLEN; ++l) {
        float S = sS[l * 64 + dl];
        float4 C4 = *(const float4*)&sC[l * 16 + n0];
        float yv = C4.x * fexp2(A2[0] * S) * H4.x
                 + C4.y * fexp2(A2[1] * S) * H4.y
                 + C4.z * fexp2(A2[2] * S) * H4.z
                 + C4.w * fexp2(A2[3] * S) * H4.w;
        yv += dpp_movf<0xB1>(yv);
        yv += dpp_movf<0x4E>(yv);
        if (q == (l & 3)) ychold = yv;
        if ((l & 3) == 3) {
            *yc += ychold;
            yc += 4 * DI;
        }
    }
}

// ---------------- merge (CrossMerge) + LayerNorm + gate, one block per (b,pos)
__global__ __launch_bounds__(384) void k_merge_ln_gate(
    const float* __restrict__ yk,
    const float* __restrict__ z1,
    const float* __restrict__ lnw,
    const float* __restrict__ lnb,
    float* __restrict__ gbuf)
{
    int pg = blockIdx.x;            // b*LL + pos
    int b = pg / LL;
    int pos = pg % LL;
    int d = threadIdx.x;
    int pt = (pos % 48) * 48 + pos / 48;

    const float* y0 = yk + ((size_t)(b * 4 + 0) * LL + pos) * DI;
    const float* y1 = yk + ((size_t)(b * 4 + 1) * LL + pt) * DI;
    const float* y2 = yk + ((size_t)(b * 4 + 2) * LL + (LL - 1 - pos)) * DI;
    const float* y3 = yk + ((size_t)(b * 4 + 3) * LL + (LL - 1 - pt)) * DI;
    float v = y0[d] + y1[d] + y2[d] + y3[d];

    float s = v, qq = v * v;
    #pragma unroll
    for (int o = 32; o >= 1; o >>= 1) {
        s += __shfl_xor(s, o, 64);
        qq += __shfl_xor(qq, o, 64);
    }
    __shared__ float ssum[6], sqq[6];
    int lane = d & 63, w = d >> 6;
    if (lane == 0) { ssum[w] = s; sqq[w] = qq; }
    __syncthreads();
    float ts = 0.f, tq = 0.f;
    #pragma unroll
    for (int i = 0; i < 6; ++i) { ts += ssum[i]; tq += sqq[i]; }
    float mu = ts / (float)DI;
    float var = tq / (float)DI - mu * mu;
    float inv = rsqrtf(var + 1e-5f);
    float y = (v - mu) * inv * lnw[d] + lnb[d];
    gbuf[(size_t)pg * DI + d] = y * z1[(size_t)pg * DI + d];
}

// ---------------- K6: out_proj -> register-tiled GEMM 64x64 (K=DI)
__global__ __launch_bounds__(256) void k_outproj(const float* __restrict__ gbuf,
                                                 const float* __restrict__ w,
                                                 float* __restrict__ out) {
    __shared__ float As[16][68];
    __shared__ float Bs[16][68];
    int o0 = blockIdx.x * 64;
    int l0 = blockIdx.y * 64;
    int b  = blockIdx.z;
    int t = threadIdx.x;
    int tx = t & 15, ty = t >> 4;
    float acc[4][4] = {{0.f}};
    int lo_o = t >> 2, kq = (t & 3) << 2;    // W loader
    int lo_l = t >> 2, d4 = (t & 3) << 2;    // G loader
    const float* wp = w + (size_t)(o0 + lo_o) * DI + kq;
    const float* gp = gbuf + ((size_t)(b * LL + l0 + lo_l)) * DI + d4;
    for (int k0 = 0; k0 < DI; k0 += 16) {
        float4 wv = *(const float4*)wp; wp += 16;
        float4 gv = *(const float4*)gp; gp += 16;
        As[kq + 0][lo_o] = wv.x; As[kq + 1][lo_o] = wv.y;
        As[kq + 2][lo_o] = wv.z; As[kq + 3][lo_o] = wv.w;
        Bs[d4 + 0][lo_l] = gv.x; Bs[d4 + 1][lo_l] = gv.y;
        Bs[d4 + 2][lo_l] = gv.z; Bs[d4 + 3][lo_l] = gv.w;
        __syncthreads();
        #pragma unroll
        for (int k = 0; k < 16; ++k) {
            float4 a  = *(const float4*)&As[k][ty * 4];
            float4 bv = *(const float4*)&Bs[k][tx * 4];
            acc[0][0] += a.x * bv.x; acc[0][1] += a.x * bv.y;
            acc[0][2] += a.x * bv.z; acc[0][3] += a.x * bv.w;
            acc[1][0] += a.y * bv.x; acc[1][1] += a.y * bv.y;
            acc[1][2] += a.y * bv.z; acc[1][3] += a.y * bv.w;
            acc[2][0] += a.z * bv.x; acc[2][1] += a.z * bv.y;
            acc[2][2] += a.z * bv.z; acc[2][3] += a.z * bv.w;
            acc[3][0] += a.w * bv.x; acc[3][1] += a.w * bv.y;
            acc[3][2] += a.w * bv.z; acc[3][3] += a.w * bv.w;
        }
        __syncthreads();
    }
    float* base = out + (size_t)(b * DM + o0 + ty * 4) * LL + l0 + tx * 4;
    #pragma unroll
    for (int io = 0; io < 4; ++io) {
        float4 v = { acc[io][0], acc[io][1], acc[io][2], acc[io][3] };
        *(float4*)(base + (size_t)io * LL) = v;
    }
}

extern "C" void kernel_launch(void* const* d_in, const int* in_sizes, int n_in,
                              void* d_out, int out_size, void* d_ws, size_t ws_size,
                              hipStream_t stream) {
    (void)in_sizes; (void)n_in; (void)out_size; (void)ws_size;
    const float* x      = (const float*)d_in[0];
    const float* ipw    = (const float*)d_in[1];
    const float* cw     = (const float*)d_in[2];
    const float* cb     = (const float*)d_in[3];
    const float* xpw    = (const float*)d_in[4];
    const float* dtw    = (const float*)d_in[5];
    const float* dtb    = (const float*)d_in[6];
    const float* Alogs  = (const float*)d_in[7];
    const float* Ds     = (const float*)d_in[8];
    const float* lnw    = (const float*)d_in[9];
    const float* lnb    = (const float*)d_in[10];
    const float* opw    = (const float*)d_in[11];
    float* out = (float*)d_out;

    float* wsf = (float*)d_ws;
    const size_t SZ  = (size_t)BQ * DI * LL;              // 3,538,944
    const size_t DTS = (size_t)BQ * KK * LL * RR;
    const size_t BCS = (size_t)BQ * KK * LL * NN;
    const size_t SBF = (size_t)BQ * KK * LL * DI;         // 14,155,776
    const size_t HST = (size_t)BQ * KK * CH * DI * NN;    //  4,718,592

    float* z1      = wsf;                 // (B,L,DI)
    float* bufA    = z1 + SZ;             // xc_pre, then xcT
    float* bufB    = bufA + SZ;           // xc_conv, then gbuf
    float* dts     = bufB + SZ;           // (B,K,L,R)
    float* Bsb     = dts + DTS;           // (B,K,L,N)
    float* Csb     = Bsb + BCS;           // (B,K,L,N)
    float* Sbuf    = Csb + BCS;           // (B,K,L,DI)
    float* hstin   = Sbuf + SBF;          // (B,K,CH,DI,N)
    float* yk      = hstin + HST;         // (B,K,L,DI)

    float* xc_pre  = bufA;
    float* xc_conv = bufB;
    float* xcT     = bufA;                // overwrites xc_pre (dead after dwconv)
    float* gbuf    = bufB;                // overwrites xc_conv (dead after staging)

    k_inproj<<<dim3(12, 36, BQ), 256, 0, stream>>>(x, ipw, xc_pre, z1);
    k_dwconv<<<(BQ * DI * HH * (WW / 4) + 255) / 256, 256, 0, stream>>>(
        xc_pre, cw, cb, xc_conv);
    k_transpose<<<BQ * 72 * 12, 256, 0, stream>>>(xc_conv, xcT);
    k_xproj<<<BQ * KK * (LL / 16), 256, 0, stream>>>(xcT, xpw, dts, Bsb, Csb);

    k_scan_pass1<<<BQ * KK * CH * 6, 256, 0, stream>>>(
        xcT, dts, Bsb, Csb, dtw, dtb, Alogs, Ds, Sbuf, hstin, yk);
    k_scan_combine<<<(BQ * KK * DI * NN) / 256, 256, 0, stream>>>(
        hstin, Sbuf, Alogs);
    k_corr<<<BQ * KK * CH * 6, 256, 0, stream>>>(Csb, Sbuf, hstin, Alogs, yk);
    k_merge_ln_gate<<<BQ * LL, 384, 0, stream>>>(yk, z1, lnw, lnb, gbuf);

    k_outproj<<<dim3(3, 36, BQ), 256, 0, stream>>>(gbuf, opw, out);
}

// Round 10
// 351.620 us; speedup vs baseline: 1.9157x; 1.1183x over previous
//
#include <hip/hip_runtime.h>
#include <math.h>

#define BQ 4
#define DM 192
#define DI 384
#define HH 48
#define WW 48
#define LL 2304
#define KK 4
#define NN 16
#define RR 12
#define CH 48      // chunks per sequence
#define CLEN 48    // chunk length

#define LOG2E 1.4426950408889634f

typedef short v8s __attribute__((ext_vector_type(8)));
typedef float v4f __attribute__((ext_vector_type(4)));

__device__ __forceinline__ float gelu_exact(float x) {
    return 0.5f * x * (1.0f + erff(x * 0.7071067811865476f));
}

__device__ __forceinline__ float softplus_f(float x) {
    return fmaxf(x, 0.0f) + log1pf(expf(-fabsf(x)));
}

__device__ __forceinline__ int pos_for(int k, int l) {
    if (k == 0) return l;
    if (k == 1) { return (l % HH) * WW + (l / HH); }
    if (k == 2) return (LL - 1) - l;
    int j = (LL - 1) - l;
    return (j % HH) * WW + (j / HH);
}

__device__ __forceinline__ float fexp2(float x) {
    return __builtin_amdgcn_exp2f(x);
}

__device__ __forceinline__ short f2bf(float x) {
    unsigned u = __float_as_uint(x);
    unsigned r = (u + 0x7FFFu + ((u >> 16) & 1u)) >> 16;
    return (short)r;
}

// DPP move: 0x00-0xFF quad_perm; 0xB1 = quad xor1, 0x4E = quad xor2.
template<int CTRL>
__device__ __forceinline__ float dpp_movf(float v) {
    return __int_as_float(__builtin_amdgcn_update_dpp(
        0, __float_as_int(v), CTRL, 0xF, 0xF, true));
}

// ---------------- P1: cast in_proj + out_proj weights to bf16 (layouts kept)
__global__ __launch_bounds__(256) void k_prep_w(const float* __restrict__ ipw,
                                                const float* __restrict__ opw,
                                                short* __restrict__ wibf,
                                                short* __restrict__ owbf) {
    int i = blockIdx.x * 256 + threadIdx.x;     // 864*256 = 221184 exactly
    if (i < 768 * 192) wibf[i] = f2bf(ipw[i]);
    else               owbf[i - 768 * 192] = f2bf(opw[i - 768 * 192]);
}

// ---------------- P2: transpose-cast x (B,192,L) -> xTbf (B,L,192) bf16
__global__ __launch_bounds__(256) void k_prep_xT(const float* __restrict__ x,
                                                 short* __restrict__ xTbf) {
    __shared__ float T[32][33];
    int blk = blockIdx.x;           // (b*72 + lt)*6 + dt
    int dt = blk % 6;
    int lt = (blk / 6) % 72;
    int b  = blk / (6 * 72);
    int d0 = dt * 32, l0 = lt * 32;
    int tx = threadIdx.x & 31, ty = threadIdx.x >> 5;   // ty 0..7
    #pragma unroll
    for (int i = 0; i < 4; ++i) {
        int dd = ty + 8 * i;
        T[dd][tx] = x[(size_t)(b * DM + d0 + dd) * LL + l0 + tx];
    }
    __syncthreads();
    #pragma unroll
    for (int i = 0; i < 4; ++i) {
        int ll = ty + 8 * i;
        xTbf[(size_t)(b * LL + l0 + ll) * DM + d0 + tx] = f2bf(T[tx][ll]);
    }
}

// ---------------- K1: in_proj via bf16 MFMA. D[l][o]; o<384 -> xc, else gelu->z.
// Block tile: 128 l x 64 o, 4 waves (wave = 32 l), K=192 in 6 chunks of 32.
__global__ __launch_bounds__(256) void k_inproj_mfma(
    const short* __restrict__ xTbf,   // (B,L,192) bf16
    const short* __restrict__ wibf,   // (768,192) bf16
    float* __restrict__ xcz)          // (B,L,768) fp32
{
    __shared__ short sA[128 * 40];    // [l][k32], row stride 40 shorts (80B)
    __shared__ short sB[64 * 40];     // [o][k32]
    int o0 = blockIdx.x * 64;
    int l0 = blockIdx.y * 128;
    int b  = blockIdx.z;
    int tid = threadIdx.x;
    int lane = tid & 63, wid = tid >> 6;
    int n = lane & 15, quad = lane >> 4;

    v4f acc[2][4];
    #pragma unroll
    for (int i = 0; i < 2; ++i)
        #pragma unroll
        for (int j = 0; j < 4; ++j) acc[i][j] = (v4f){0.f, 0.f, 0.f, 0.f};

    for (int kc = 0; kc < 192; kc += 32) {
        for (int i = tid; i < 512; i += 256) {          // A: 128 rows x 4 segs
            int row = i >> 2, seg = i & 3;
            *(v8s*)&sA[row * 40 + seg * 8] =
                *(const v8s*)(xTbf + (size_t)(b * LL + l0 + row) * DM + kc + seg * 8);
        }
        {                                               // B: 64 rows x 4 segs
            int row = tid >> 2, seg = tid & 3;
            *(v8s*)&sB[row * 40 + seg * 8] =
                *(const v8s*)(wibf + (size_t)(o0 + row) * DM + kc + seg * 8);
        }
        __syncthreads();
        v8s a0 = *(v8s*)&sA[(wid * 32 + n) * 40 + quad * 8];
        v8s a1 = *(v8s*)&sA[(wid * 32 + 16 + n) * 40 + quad * 8];
        #pragma unroll
        for (int os = 0; os < 4; ++os) {
            v8s bv = *(v8s*)&sB[(os * 16 + n) * 40 + quad * 8];
            acc[0][os] = __builtin_amdgcn_mfma_f32_16x16x32_bf16(a0, bv, acc[0][os], 0, 0, 0);
            acc[1][os] = __builtin_amdgcn_mfma_f32_16x16x32_bf16(a1, bv, acc[1][os], 0, 0, 0);
        }
        __syncthreads();
    }
    bool zhalf = (o0 >= DI);
    #pragma unroll
    for (int ls = 0; ls < 2; ++ls)
        #pragma unroll
        for (int os = 0; os < 4; ++os) {
            int o = o0 + os * 16 + n;
            #pragma unroll
            for (int r = 0; r < 4; ++r) {
                int l = l0 + wid * 32 + ls * 16 + quad * 4 + r;
                float v = acc[ls][os][r];
                xcz[(size_t)(b * LL + l) * 768 + o] = zhalf ? gelu_exact(v) : v;
            }
        }
}

// ---------------- K2: depthwise 3x3 conv + bias + gelu, [l][c] layout.
// Reads xcz channel-half, writes xcT (B,L,384) fp32 directly (no transpose kernel).
__global__ __launch_bounds__(384) void k_dwconv(const float* __restrict__ xcz,
                                                const float* __restrict__ cw,
                                                const float* __restrict__ cb,
                                                float* __restrict__ xcT) {
    int b = blockIdx.x / HH, h = blockIdx.x % HH;
    int d = threadIdx.x;
    const float* in = xcz + (size_t)b * LL * 768 + d;   // + l*768
    float w9[9];
    #pragma unroll
    for (int i = 0; i < 9; ++i) w9[i] = cw[d * 9 + i];
    float bias = cb[d];
    bool hm = h > 0, hp = h < HH - 1;
    int r0 = (h - 1) * WW, r1 = h * WW, r2 = (h + 1) * WW;
    float c00, c01, c02, c10, c11, c12, c20, c21, c22;
    c00 = c10 = c20 = 0.f;
    c01 = hm ? in[(size_t)(r0) * 768] : 0.f;
    c11 = in[(size_t)(r1) * 768];
    c21 = hp ? in[(size_t)(r2) * 768] : 0.f;
    c02 = hm ? in[(size_t)(r0 + 1) * 768] : 0.f;
    c12 = in[(size_t)(r1 + 1) * 768];
    c22 = hp ? in[(size_t)(r2 + 1) * 768] : 0.f;
    float* outp = xcT + (size_t)(b * LL + h * WW) * DI + d;
    for (int w = 0; w < WW; ++w) {
        float s = bias
            + w9[0] * c00 + w9[1] * c01 + w9[2] * c02
            + w9[3] * c10 + w9[4] * c11 + w9[5] * c12
            + w9[6] * c20 + w9[7] * c21 + w9[8] * c22;
        outp[(size_t)w * DI] = gelu_exact(s);
        c00 = c01; c01 = c02; c10 = c11; c11 = c12; c20 = c21; c21 = c22;
        int wn = w + 2;
        if (wn < WW) {
            c02 = hm ? in[(size_t)(r0 + wn) * 768] : 0.f;
            c12 = in[(size_t)(r1 + wn) * 768];
            c22 = hp ? in[(size_t)(r2 + wn) * 768] : 0.f;
        } else { c02 = c12 = c22 = 0.f; }
    }
}

// ---------------- K3: x_proj per direction (reads xcT, coalesced both sides)
__global__ __launch_bounds__(256) void k_xproj(const float* __restrict__ xcT,
                                               const float* __restrict__ xpw,
                                               float* __restrict__ dts,
                                               float* __restrict__ Bsb,
                                               float* __restrict__ Csb) {
    __shared__ float xt[16 * 385];
    const int nt = LL / 16;
    int l0 = (blockIdx.x % nt) * 16;
    int bk = blockIdx.x / nt;
    int k = bk % KK;
    int b = bk / KK;
    for (int idx = threadIdx.x; idx < DI * 16; idx += 256) {
        int d = idx % DI;
        int lt = idx / DI;
        int pos = pos_for(k, l0 + lt);
        xt[lt * 385 + d] = xcT[((size_t)b * LL + pos) * DI + d];
    }
    __syncthreads();
    int t = threadIdx.x;
    if (t < 176) {
        int c = t >> 2, ltq = t & 3;
        float s0 = 0.f, s1 = 0.f, s2 = 0.f, s3 = 0.f;
        const float* wr = xpw + (size_t)(k * 44 + c) * DI;
        int base = (ltq * 4) * 385;
        for (int d = 0; d < DI; ++d) {
            float wv = wr[d];
            s0 += wv * xt[base + d];
            s1 += wv * xt[base + 385 + d];
            s2 += wv * xt[base + 2 * 385 + d];
            s3 += wv * xt[base + 3 * 385 + d];
        }
        float sv[4] = {s0, s1, s2, s3};
        #pragma unroll
        for (int j = 0; j < 4; ++j) {
            int l = l0 + ltq * 4 + j;
            if (c < RR)
                dts[((size_t)bk * LL + l) * RR + c] = sv[j];
            else if (c < RR + NN)
                Bsb[((size_t)bk * LL + l) * NN + (c - RR)] = sv[j];
            else
                Csb[((size_t)bk * LL + l) * NN + (c - RR - NN)] = sv[j];
        }
    }
}

// ---------------- Single-pass chunked scan, stage-then-scan (unchanged from R8)
__global__ __launch_bounds__(256) void k_scan_pass1(
    const float* __restrict__ xcT,
    const float* __restrict__ dts,
    const float* __restrict__ Bsb,
    const float* __restrict__ Csb,
    const float* __restrict__ dtw_g,
    const float* __restrict__ dtb_g,
    const float* __restrict__ Alogs,
    const float* __restrict__ Ds_g,
    float* __restrict__ Sbuf,
    float* __restrict__ hstin,
    float* __restrict__ yk)
{
    __shared__ float sB[CLEN * 16];      // [l][n]
    __shared__ float sC[CLEN * 16];
    __shared__ float sDts[CLEN * 12];    // [l][r]
    __shared__ float sDel[CLEN * 64];    // [l][dl]
    __shared__ float sU[CLEN * 64];      // [l][dl]

    int blk = blockIdx.x;                 // ((bk*CH + c)*6 + dblk)
    int dblk = blk % 6;
    int tmp = blk / 6;
    int c = tmp % CH;
    int bk = tmp / CH;
    int k = bk & 3, b = bk >> 2;
    int tid = threadIdx.x;
    int l0 = c * CLEN;

    {
        const float4* Bg = (const float4*)(Bsb + ((size_t)bk * LL + l0) * NN);
        const float4* Cg = (const float4*)(Csb + ((size_t)bk * LL + l0) * NN);
        if (tid < CLEN * 4) {
            ((float4*)sB)[tid] = Bg[tid];
            ((float4*)sC)[tid] = Cg[tid];
        }
        const float4* Dg = (const float4*)(dts + ((size_t)bk * LL + l0) * RR);
        for (int i = tid; i < CLEN * 3; i += 256)
            ((float4*)sDts)[i] = Dg[i];
    }
    {
        const float* xb = xcT + (size_t)b * LL * DI + dblk * 64;
        #pragma unroll
        for (int it = 0; it < 3; ++it) {
            int i = it * 256 + tid;       // 768 float4
            int l = i >> 4, f4 = i & 15;
            int pos = pos_for(k, l0 + l);
            ((float4*)sU)[l * 16 + f4] = *(const float4*)(xb + (size_t)pos * DI + f4 * 4);
        }
    }
    __syncthreads();
    {
        int dl = tid & 63, lset = tid >> 6;
        int dd = dblk * 64 + dl;
        int kdq = k * DI + dd;
        float dtbv = dtb_g[kdq];
        float w12[12];
        {
            const float4* p = (const float4*)(dtw_g + (size_t)kdq * RR);
            float4 a0 = p[0], a1 = p[1], a2 = p[2];
            w12[0]=a0.x; w12[1]=a0.y; w12[2]=a0.z;  w12[3]=a0.w;
            w12[4]=a1.x; w12[5]=a1.y; w12[6]=a1.z;  w12[7]=a1.w;
            w12[8]=a2.x; w12[9]=a2.y; w12[10]=a2.z; w12[11]=a2.w;
        }
        #pragma unroll
        for (int j = 0; j < 12; ++j) {
            int l = lset * 12 + j;
            const float* dp = sDts + l * 12;
            float acc = dtbv;
            #pragma unroll
            for (int r = 0; r < 12; ++r) acc += dp[r] * w12[r];
            sDel[l * 64 + dl] = softplus_f(acc);
        }
    }
    __syncthreads();

    int lane = tid & 63, wv = tid >> 6;
    int q = lane & 3;
    int d16 = lane >> 2;
    int dl = wv * 16 + d16;
    int d = dblk * 64 + dl;
    int kd = k * DI + d;
    int n0 = q << 2;

    float4 Al = *(const float4*)(Alogs + (size_t)kd * NN + n0);
    float A2[4] = { -expf(Al.x) * LOG2E, -expf(Al.y) * LOG2E,
                    -expf(Al.z) * LOG2E, -expf(Al.w) * LOG2E };
    float Dv = Ds_g[kd];
    float* Sc = Sbuf + ((size_t)bk * LL + l0 + q) * DI + d;
    float* yc = yk   + ((size_t)bk * LL + l0 + q) * DI + d;

    float h0 = 0.f, h1 = 0.f, h2 = 0.f, h3 = 0.f;
    float td = 0.f;
    float yhold = 0.f, Shold = 0.f;

    #pragma unroll
    for (int l = 0; l < CLEN; ++l) {
        float delta = sDel[l * 64 + dl];
        float ub_b  = sU[l * 64 + dl];
        td += delta;
        float du = delta * ub_b;
        float4 B4 = *(const float4*)&sB[l * 16 + n0];
        h0 = h0 * fexp2(delta * A2[0]) + du * B4.x;
        h1 = h1 * fexp2(delta * A2[1]) + du * B4.y;
        h2 = h2 * fexp2(delta * A2[2]) + du * B4.z;
        h3 = h3 * fexp2(delta * A2[3]) + du * B4.w;
        float4 C4 = *(const float4*)&sC[l * 16 + n0];
        float yp = h0 * C4.x + h1 * C4.y + h2 * C4.z + h3 * C4.w;
        yp += dpp_movf<0xB1>(yp);
        yp += dpp_movf<0x4E>(yp);
        float yf = yp + ub_b * Dv;
        if (q == (l & 3)) { yhold = yf; Shold = td; }
        if ((l & 3) == 3) {
            *yc = yhold; *Sc = Shold;
            yc += 4 * DI; Sc += 4 * DI;
        }
    }

    float4 h4; h4.x = h0; h4.y = h1; h4.z = h2; h4.w = h3;
    *(float4*)(hstin + ((size_t)(bk * CH + c) * DI + d) * NN + n0) = h4;
}

// ---------------- combine (in-place): end-states -> incoming states
__global__ __launch_bounds__(256) void k_scan_combine(
    float* __restrict__ hstin,
    const float* __restrict__ Sbuf,
    const float* __restrict__ Alogs)
{
    int t = blockIdx.x * 256 + threadIdx.x;   // B*K*DI*NN = 98304
    int n = t & 15;
    int d = (t >> 4) % DI;
    int bk = t / (DI * NN);
    int k = bk & 3;
    float A2 = -expf(Alogs[(size_t)(k * DI + d) * NN + n]) * LOG2E;
    float h = 0.f;
    for (int c = 0; c < CH; ++c) {
        size_t rb = (size_t)(bk * CH + c) * DI + d;
        float hend = hstin[rb * NN + n];
        hstin[rb * NN + n] = h;
        float St = Sbuf[((size_t)bk * LL + c * CLEN + CLEN - 1) * DI + d];
        h = fexp2(A2 * St) * h + hend;
    }
}

// ---------------- correction: stage C,S in LDS, plain RMW on exclusive region
__global__ __launch_bounds__(256) void k_corr(
    const float* __restrict__ Csb,
    const float* __restrict__ Sbuf,
    const float* __restrict__ hin,
    const float* __restrict__ Alogs,
    float* __restrict__ yk)
{
    __shared__ float sC[CLEN * 16];      // [l][n]
    __shared__ float sS[CLEN * 64];      // [l][dl]

    int blk = blockIdx.x;                 // ((bk*CH + c)*6 + dblk)
    int dblk = blk % 6;
    int tmp = blk / 6;
    int c = tmp % CH;
    if (c == 0) return;
    int bk = tmp / CH;
    int k = bk & 3;
    int tid = threadIdx.x;
    int l0 = c * CLEN;

    {
        const float4* Cg = (const float4*)(Csb + ((size_t)bk * LL + l0) * NN);
        if (tid < CLEN * 4) ((float4*)sC)[tid] = Cg[tid];
        const float* Sg = Sbuf + ((size_t)bk * LL + l0) * DI + dblk * 64;
        #pragma unroll
        for (int it = 0; it < 3; ++it) {
            int i = it * 256 + tid;       // 768 float4
            int l = i >> 4, f4 = i & 15;
            ((float4*)sS)[l * 16 + f4] = *(const float4*)(Sg + (size_t)l * DI + f4 * 4);
        }
    }
    __syncthreads();

    int lane = tid & 63, wv = tid >> 6;
    int q = lane & 3;
    int d16 = lane >> 2;
    int dl = wv * 16 + d16;
    int d = dblk * 64 + dl;
    int kd = k * DI + d;
    int n0 = q << 2;

    float4 Al = *(const float4*)(Alogs + (size_t)kd * NN + n0);
    float A2[4] = { -expf(Al.x) * LOG2E, -expf(Al.y) * LOG2E,
                    -expf(Al.z) * LOG2E, -expf(Al.w) * LOG2E };
    float4 H4 = *(const float4*)(hin + ((size_t)(bk * CH + c) * DI + d) * NN + n0);
    float* yc = yk + ((size_t)bk * LL + l0 + q) * DI + d;

    float ychold = 0.f;
    #pragma unroll
    for (int l = 0; l < CLEN; ++l) {
        float S = sS[l * 64 + dl];
        float4 C4 = *(const float4*)&sC[l * 16 + n0];
        float yv = C4.x * fexp2(A2[0] * S) * H4.x
                 + C4.y * fexp2(A2[1] * S) * H4.y
                 + C4.z * fexp2(A2[2] * S) * H4.z
                 + C4.w * fexp2(A2[3] * S) * H4.w;
        yv += dpp_movf<0xB1>(yv);
        yv += dpp_movf<0x4E>(yv);
        if (q == (l & 3)) ychold = yv;
        if ((l & 3) == 3) {
            *yc += ychold;
            yc += 4 * DI;
        }
    }
}

// ---------------- merge (CrossMerge) + LayerNorm + gate -> bf16 gbuf
__global__ __launch_bounds__(384) void k_merge_ln_gate(
    const float* __restrict__ yk,
    const float* __restrict__ xcz,     // z at columns 384..767
    const float* __restrict__ lnw,
    const float* __restrict__ lnb,
    short* __restrict__ gbufb)
{
    int pg = blockIdx.x;            // b*LL + pos
    int b = pg / LL;
    int pos = pg % LL;
    int d = threadIdx.x;
    int pt = (pos % 48) * 48 + pos / 48;

    const float* y0 = yk + ((size_t)(b * 4 + 0) * LL + pos) * DI;
    const float* y1 = yk + ((size_t)(b * 4 + 1) * LL + pt) * DI;
    const float* y2 = yk + ((size_t)(b * 4 + 2) * LL + (LL - 1 - pos)) * DI;
    const float* y3 = yk + ((size_t)(b * 4 + 3) * LL + (LL - 1 - pt)) * DI;
    float v = y0[d] + y1[d] + y2[d] + y3[d];

    float s = v, qq = v * v;
    #pragma unroll
    for (int o = 32; o >= 1; o >>= 1) {
        s += __shfl_xor(s, o, 64);
        qq += __shfl_xor(qq, o, 64);
    }
    __shared__ float ssum[6], sqq[6];
    int lane = d & 63, w = d >> 6;
    if (lane == 0) { ssum[w] = s; sqq[w] = qq; }
    __syncthreads();
    float ts = 0.f, tq = 0.f;
    #pragma unroll
    for (int i = 0; i < 6; ++i) { ts += ssum[i]; tq += sqq[i]; }
    float mu = ts / (float)DI;
    float var = tq / (float)DI - mu * mu;
    float inv = rsqrtf(var + 1e-5f);
    float y = (v - mu) * inv * lnw[d] + lnb[d];
    float z = xcz[(size_t)pg * 768 + DI + d];
    gbufb[(size_t)pg * DI + d] = f2bf(y * z);
}

// ---------------- K6: out_proj via bf16 MFMA. K=384, tile 128l x 64o.
__global__ __launch_bounds__(256) void k_outproj_mfma(
    const short* __restrict__ gbufb,   // (B,L,384) bf16
    const short* __restrict__ owbf,    // (192,384) bf16
    float* __restrict__ out)           // (B,192,L) fp32
{
    __shared__ short sA[128 * 40];
    __shared__ short sB[64 * 40];
    int o0 = blockIdx.x * 64;
    int l0 = blockIdx.y * 128;
    int b  = blockIdx.z;
    int tid = threadIdx.x;
    int lane = tid & 63, wid = tid >> 6;
    int n = lane & 15, quad = lane >> 4;

    v4f acc[2][4];
    #pragma unroll
    for (int i = 0; i < 2; ++i)
        #pragma unroll
        for (int j = 0; j < 4; ++j) acc[i][j] = (v4f){0.f, 0.f, 0.f, 0.f};

    for (int kc = 0; kc < DI; kc += 32) {
        for (int i = tid; i < 512; i += 256) {
            int row = i >> 2, seg = i & 3;
            *(v8s*)&sA[row * 40 + seg * 8] =
                *(const v8s*)(gbufb + (size_t)(b * LL + l0 + row) * DI + kc + seg * 8);
        }
        {
            int row = tid >> 2, seg = tid & 3;
            *(v8s*)&sB[row * 40 + seg * 8] =
                *(const v8s*)(owbf + (size_t)(o0 + row) * DI + kc + seg * 8);
        }
        __syncthreads();
        v8s a0 = *(v8s*)&sA[(wid * 32 + n) * 40 + quad * 8];
        v8s a1 = *(v8s*)&sA[(wid * 32 + 16 + n) * 40 + quad * 8];
        #pragma unroll
        for (int os = 0; os < 4; ++os) {
            v8s bv = *(v8s*)&sB[(os * 16 + n) * 40 + quad * 8];
            acc[0][os] = __builtin_amdgcn_mfma_f32_16x16x32_bf16(a0, bv, acc[0][os], 0, 0, 0);
            acc[1][os] = __builtin_amdgcn_mfma_f32_16x16x32_bf16(a1, bv, acc[1][os], 0, 0, 0);
        }
        __syncthreads();
    }
    #pragma unroll
    for (int ls = 0; ls < 2; ++ls)
        #pragma unroll
        for (int os = 0; os < 4; ++os) {
            int o = o0 + os * 16 + n;
            #pragma unroll
            for (int r = 0; r < 4; ++r) {
                int l = l0 + wid * 32 + ls * 16 + quad * 4 + r;
                out[(size_t)(b * DM + o) * LL + l] = acc[ls][os][r];
            }
        }
}

extern "C" void kernel_launch(void* const* d_in, const int* in_sizes, int n_in,
                              void* d_out, int out_size, void* d_ws, size_t ws_size,
                              hipStream_t stream) {
    (void)in_sizes; (void)n_in; (void)out_size; (void)ws_size;
    const float* x      = (const float*)d_in[0];
    const float* ipw    = (const float*)d_in[1];
    const float* cw     = (const float*)d_in[2];
    const float* cb     = (const float*)d_in[3];
    const float* xpw    = (const float*)d_in[4];
    const float* dtw    = (const float*)d_in[5];
    const float* dtb    = (const float*)d_in[6];
    const float* Alogs  = (const float*)d_in[7];
    const float* Ds     = (const float*)d_in[8];
    const float* lnw    = (const float*)d_in[9];
    const float* lnb    = (const float*)d_in[10];
    const float* opw    = (const float*)d_in[11];
    float* out = (float*)d_out;

    float* wsf = (float*)d_ws;
    const size_t XCZ = (size_t)BQ * LL * 768;             //  7,077,888
    const size_t SZ  = (size_t)BQ * DI * LL;              //  3,538,944
    const size_t DTS = (size_t)BQ * KK * LL * RR;         //    442,368
    const size_t BCS = (size_t)BQ * KK * LL * NN;         //    589,824
    const size_t SBF = (size_t)BQ * KK * LL * DI;         // 14,155,776
    const size_t HST = (size_t)BQ * KK * CH * DI * NN;    //  4,718,592

    float* xcz   = wsf;                  // (B,L,768): xc half + gelu(z) half
    float* xcT   = xcz + XCZ;            // (B,L,384) conv output (scan layout)
    float* dts   = xcT + SZ;             // (B,K,L,R)
    float* Bsb   = dts + DTS;            // (B,K,L,N)
    float* Csb   = Bsb + BCS;            // (B,K,L,N)
    float* Sbuf  = Csb + BCS;            // (B,K,L,DI)
    float* hstin = Sbuf + SBF;           // (B,K,CH,DI,N)
    float* yk    = hstin + HST;          // (B,K,L,DI)
    short* xTbf  = (short*)(yk + SBF);   // (B,L,192) bf16 in_proj input
    short* wibf  = xTbf + (size_t)BQ * LL * DM;   // (768,192)
    short* owbf  = wibf + 768 * 192;              // (192,384)
    // gbufb needs B*L*384 shorts. R9 BUG: aliasing it to xTbf overran into
    // wibf/owbf (xTbf is only B*L*192 shorts). Alias Sbuf instead: Sbuf's
    // last reader is k_corr, which completes before k_merge_ln_gate writes.
    short* gbufb = (short*)Sbuf;

    k_prep_w<<<864, 256, 0, stream>>>(ipw, opw, wibf, owbf);
    k_prep_xT<<<BQ * 72 * 6, 256, 0, stream>>>(x, xTbf);
    k_inproj_mfma<<<dim3(12, 18, BQ), 256, 0, stream>>>(xTbf, wibf, xcz);
    k_dwconv<<<BQ * HH, 384, 0, stream>>>(xcz, cw, cb, xcT);
    k_xproj<<<BQ * KK * (LL / 16), 256, 0, stream>>>(xcT, xpw, dts, Bsb, Csb);

    k_scan_pass1<<<BQ * KK * CH * 6, 256, 0, stream>>>(
        xcT, dts, Bsb, Csb, dtw, dtb, Alogs, Ds, Sbuf, hstin, yk);
    k_scan_combine<<<(BQ * KK * DI * NN) / 256, 256, 0, stream>>>(
        hstin, Sbuf, Alogs);
    k_corr<<<BQ * KK * CH * 6, 256, 0, stream>>>(Csb, Sbuf, hstin, Alogs, yk);
    k_merge_ln_gate<<<BQ * LL, 384, 0, stream>>>(yk, xcz, lnw, lnb, gbufb);

    k_outproj_mfma<<<dim3(3, 18, BQ), 256, 0, stream>>>(gbufb, owbf, out);
}

// Round 11
// 302.622 us; speedup vs baseline: 2.2259x; 1.1619x over previous
//
#include <hip/hip_runtime.h>
#include <math.h>

#define BQ 4
#define DM 192
#define DI 384
#define HH 48
#define WW 48
#define LL 2304
#define KK 4
#define NN 16
#define RR 12
#define CH 48      // chunks per sequence
#define CLEN 48    // chunk length

#define LOG2E 1.4426950408889634f

typedef short v8s __attribute__((ext_vector_type(8)));
typedef float v4f __attribute__((ext_vector_type(4)));

__device__ __forceinline__ float gelu_exact(float x) {
    return 0.5f * x * (1.0f + erff(x * 0.7071067811865476f));
}

__device__ __forceinline__ float softplus_f(float x) {
    return fmaxf(x, 0.0f) + log1pf(expf(-fabsf(x)));
}

__device__ __forceinline__ int pos_for(int k, int l) {
    if (k == 0) return l;
    if (k == 1) { return (l % HH) * WW + (l / HH); }
    if (k == 2) return (LL - 1) - l;
    int j = (LL - 1) - l;
    return (j % HH) * WW + (j / HH);
}

__device__ __forceinline__ int pt_of(int p) {   // 48x48 transpose, involution
    return (p % 48) * 48 + p / 48;
}

__device__ __forceinline__ float fexp2(float x) {
    return __builtin_amdgcn_exp2f(x);
}

__device__ __forceinline__ short f2bf(float x) {
    unsigned u = __float_as_uint(x);
    unsigned r = (u + 0x7FFFu + ((u >> 16) & 1u)) >> 16;
    return (short)r;
}

// DPP move: 0x00-0xFF quad_perm; 0xB1 = quad xor1, 0x4E = quad xor2.
template<int CTRL>
__device__ __forceinline__ float dpp_movf(float v) {
    return __int_as_float(__builtin_amdgcn_update_dpp(
        0, __float_as_int(v), CTRL, 0xF, 0xF, true));
}

// ---------------- P1: cast weights to bf16. wpbf = x_proj (176,384) padded to 192 rows.
__global__ __launch_bounds__(256) void k_prep_w(const float* __restrict__ ipw,
                                                const float* __restrict__ opw,
                                                const float* __restrict__ xpw,
                                                short* __restrict__ wibf,
                                                short* __restrict__ owbf,
                                                short* __restrict__ wpbf) {
    int i = blockIdx.x * 256 + threadIdx.x;     // 1152*256 = 294912 exactly
    if (i < 147456)       wibf[i] = f2bf(ipw[i]);
    else if (i < 221184)  owbf[i - 147456] = f2bf(opw[i - 147456]);
    else if (i < 288768)  wpbf[i - 221184] = f2bf(xpw[i - 221184]);
    else                  wpbf[67584 + (i - 288768)] = 0;   // pad rows 176..191
}

// ---------------- P2: transpose-cast x (B,192,L) -> xTbf (B,L,192) bf16
__global__ __launch_bounds__(256) void k_prep_xT(const float* __restrict__ x,
                                                 short* __restrict__ xTbf) {
    __shared__ float T[32][33];
    int blk = blockIdx.x;           // (b*72 + lt)*6 + dt
    int dt = blk % 6;
    int lt = (blk / 6) % 72;
    int b  = blk / (6 * 72);
    int d0 = dt * 32, l0 = lt * 32;
    int tx = threadIdx.x & 31, ty = threadIdx.x >> 5;   // ty 0..7
    #pragma unroll
    for (int i = 0; i < 4; ++i) {
        int dd = ty + 8 * i;
        T[dd][tx] = x[(size_t)(b * DM + d0 + dd) * LL + l0 + tx];
    }
    __syncthreads();
    #pragma unroll
    for (int i = 0; i < 4; ++i) {
        int ll = ty + 8 * i;
        xTbf[(size_t)(b * LL + l0 + ll) * DM + d0 + tx] = f2bf(T[tx][ll]);
    }
}

// ---------------- K1: in_proj via bf16 MFMA. D[l][o]; o<384 -> xc, else gelu->z.
__global__ __launch_bounds__(256) void k_inproj_mfma(
    const short* __restrict__ xTbf,   // (B,L,192) bf16
    const short* __restrict__ wibf,   // (768,192) bf16
    float* __restrict__ xcz)          // (B,L,768) fp32
{
    __shared__ short sA[128 * 40];    // [l][k32], row stride 40 shorts
    __shared__ short sB[64 * 40];     // [o][k32]
    int o0 = blockIdx.x * 64;
    int l0 = blockIdx.y * 128;
    int b  = blockIdx.z;
    int tid = threadIdx.x;
    int lane = tid & 63, wid = tid >> 6;
    int n = lane & 15, quad = lane >> 4;

    v4f acc[2][4];
    #pragma unroll
    for (int i = 0; i < 2; ++i)
        #pragma unroll
        for (int j = 0; j < 4; ++j) acc[i][j] = (v4f){0.f, 0.f, 0.f, 0.f};

    for (int kc = 0; kc < 192; kc += 32) {
        for (int i = tid; i < 512; i += 256) {
            int row = i >> 2, seg = i & 3;
            *(v8s*)&sA[row * 40 + seg * 8] =
                *(const v8s*)(xTbf + (size_t)(b * LL + l0 + row) * DM + kc + seg * 8);
        }
        {
            int row = tid >> 2, seg = tid & 3;
            *(v8s*)&sB[row * 40 + seg * 8] =
                *(const v8s*)(wibf + (size_t)(o0 + row) * DM + kc + seg * 8);
        }
        __syncthreads();
        v8s a0 = *(v8s*)&sA[(wid * 32 + n) * 40 + quad * 8];
        v8s a1 = *(v8s*)&sA[(wid * 32 + 16 + n) * 40 + quad * 8];
        #pragma unroll
        for (int os = 0; os < 4; ++os) {
            v8s bv = *(v8s*)&sB[(os * 16 + n) * 40 + quad * 8];
            acc[0][os] = __builtin_amdgcn_mfma_f32_16x16x32_bf16(a0, bv, acc[0][os], 0, 0, 0);
            acc[1][os] = __builtin_amdgcn_mfma_f32_16x16x32_bf16(a1, bv, acc[1][os], 0, 0, 0);
        }
        __syncthreads();
    }
    bool zhalf = (o0 >= DI);
    #pragma unroll
    for (int ls = 0; ls < 2; ++ls)
        #pragma unroll
        for (int os = 0; os < 4; ++os) {
            int o = o0 + os * 16 + n;
            #pragma unroll
            for (int r = 0; r < 4; ++r) {
                int l = l0 + wid * 32 + ls * 16 + quad * 4 + r;
                float v = acc[ls][os][r];
                xcz[(size_t)(b * LL + l) * 768 + o] = zhalf ? gelu_exact(v) : v;
            }
        }
}

// ---------------- K2: depthwise 3x3 conv + bias + gelu, [l][c] layout.
// 4 w-segments per (b,h) for parallelism. Writes xcT fp32 + xcTbf bf16.
__global__ __launch_bounds__(384) void k_dwconv(const float* __restrict__ xcz,
                                                const float* __restrict__ cw,
                                                const float* __restrict__ cb,
                                                float* __restrict__ xcT,
                                                short* __restrict__ xcTbf) {
    int blk = blockIdx.x;           // ((b*HH + h)*4 + seg)
    int seg = blk & 3;
    int bh = blk >> 2;
    int b = bh / HH, h = bh % HH;
    int d = threadIdx.x;
    int w0 = seg * 12;
    const float* in = xcz + (size_t)b * LL * 768 + d;
    float w9[9];
    #pragma unroll
    for (int i = 0; i < 9; ++i) w9[i] = cw[d * 9 + i];
    float bias = cb[d];
    bool hm = h > 0, hp = h < HH - 1;
    int r0 = (h - 1) * WW, r1 = h * WW, r2 = (h + 1) * WW;
    float c00, c01, c02, c10, c11, c12, c20, c21, c22;
    bool wl = (w0 > 0);
    c00 = (hm && wl) ? in[(size_t)(r0 + w0 - 1) * 768] : 0.f;
    c10 = wl ? in[(size_t)(r1 + w0 - 1) * 768] : 0.f;
    c20 = (hp && wl) ? in[(size_t)(r2 + w0 - 1) * 768] : 0.f;
    c01 = hm ? in[(size_t)(r0 + w0) * 768] : 0.f;
    c11 = in[(size_t)(r1 + w0) * 768];
    c21 = hp ? in[(size_t)(r2 + w0) * 768] : 0.f;
    c02 = hm ? in[(size_t)(r0 + w0 + 1) * 768] : 0.f;
    c12 = in[(size_t)(r1 + w0 + 1) * 768];
    c22 = hp ? in[(size_t)(r2 + w0 + 1) * 768] : 0.f;
    #pragma unroll
    for (int wi = 0; wi < 12; ++wi) {
        int w = w0 + wi;
        float s = bias
            + w9[0] * c00 + w9[1] * c01 + w9[2] * c02
            + w9[3] * c10 + w9[4] * c11 + w9[5] * c12
            + w9[6] * c20 + w9[7] * c21 + w9[8] * c22;
        float v = gelu_exact(s);
        size_t row = (size_t)(b * LL + h * WW + w);
        xcT[row * DI + d] = v;
        xcTbf[row * DI + d] = f2bf(v);
        c00 = c01; c01 = c02; c10 = c11; c11 = c12; c20 = c21; c21 = c22;
        int wn = w + 2;
        bool okw = wn < WW;
        c02 = (hm && okw) ? in[(size_t)(r0 + wn) * 768] : 0.f;
        c12 = okw ? in[(size_t)(r1 + wn) * 768] : 0.f;
        c22 = (hp && okw) ? in[(size_t)(r2 + wn) * 768] : 0.f;
    }
}

// ---------------- K3: x_proj, ALL 4 directions as ONE bf16 MFMA GEMM.
// Q[c_all][l'] = W[c_all]·xcT[l'], c_all = k*44+c; scatter epilogue maps
// l' -> scan-l per direction (k0: l', k1: pt(l'), k2: L-1-l', k3: L-1-pt(l')).
__global__ __launch_bounds__(256) void k_xproj_mfma(
    const short* __restrict__ xcTbf,  // (B,L,384) bf16
    const short* __restrict__ wpbf,   // (192,384) bf16, rows>=176 zero
    float* __restrict__ dts,
    float* __restrict__ Bsb,
    float* __restrict__ Csb)
{
    __shared__ short sA[128 * 40];
    __shared__ short sB[64 * 40];
    int o0 = blockIdx.x * 64;
    int l0 = blockIdx.y * 128;
    int b  = blockIdx.z;
    int tid = threadIdx.x;
    int lane = tid & 63, wid = tid >> 6;
    int n = lane & 15, quad = lane >> 4;

    v4f acc[2][4];
    #pragma unroll
    for (int i = 0; i < 2; ++i)
        #pragma unroll
        for (int j = 0; j < 4; ++j) acc[i][j] = (v4f){0.f, 0.f, 0.f, 0.f};

    for (int kc = 0; kc < DI; kc += 32) {
        for (int i = tid; i < 512; i += 256) {
            int row = i >> 2, seg = i & 3;
            *(v8s*)&sA[row * 40 + seg * 8] =
                *(const v8s*)(xcTbf + (size_t)(b * LL + l0 + row) * DI + kc + seg * 8);
        }
        {
            int row = tid >> 2, seg = tid & 3;
            *(v8s*)&sB[row * 40 + seg * 8] =
                *(const v8s*)(wpbf + (size_t)(o0 + row) * DI + kc + seg * 8);
        }
        __syncthreads();
        v8s a0 = *(v8s*)&sA[(wid * 32 + n) * 40 + quad * 8];
        v8s a1 = *(v8s*)&sA[(wid * 32 + 16 + n) * 40 + quad * 8];
        #pragma unroll
        for (int os = 0; os < 4; ++os) {
            v8s bv = *(v8s*)&sB[(os * 16 + n) * 40 + quad * 8];
            acc[0][os] = __builtin_amdgcn_mfma_f32_16x16x32_bf16(a0, bv, acc[0][os], 0, 0, 0);
            acc[1][os] = __builtin_amdgcn_mfma_f32_16x16x32_bf16(a1, bv, acc[1][os], 0, 0, 0);
        }
        __syncthreads();
    }
    #pragma unroll
    for (int ls = 0; ls < 2; ++ls)
        #pragma unroll
        for (int os = 0; os < 4; ++os) {
            int c_all = o0 + os * 16 + n;
            if (c_all >= 176) continue;
            int k = c_all / 44;
            int c = c_all - k * 44;
            int bk = b * 4 + k;
            #pragma unroll
            for (int r = 0; r < 4; ++r) {
                int lp = l0 + wid * 32 + ls * 16 + quad * 4 + r;
                int lk = (k == 0) ? lp
                       : (k == 1) ? pt_of(lp)
                       : (k == 2) ? (LL - 1 - lp)
                                  : (LL - 1 - pt_of(lp));
                float v = acc[ls][os][r];
                size_t base = (size_t)bk * LL + lk;
                if (c < RR)           dts[base * RR + c] = v;
                else if (c < RR + NN) Bsb[base * NN + (c - RR)] = v;
                else                  Csb[base * NN + (c - RR - NN)] = v;
            }
        }
}

// ---------------- Single-pass chunked scan, stage-then-scan (unchanged)
__global__ __launch_bounds__(256) void k_scan_pass1(
    const float* __restrict__ xcT,
    const float* __restrict__ dts,
    const float* __restrict__ Bsb,
    const float* __restrict__ Csb,
    const float* __restrict__ dtw_g,
    const float* __restrict__ dtb_g,
    const float* __restrict__ Alogs,
    const float* __restrict__ Ds_g,
    float* __restrict__ Sbuf,
    float* __restrict__ hstin,
    float* __restrict__ yk)
{
    __shared__ float sB[CLEN * 16];      // [l][n]
    __shared__ float sC[CLEN * 16];
    __shared__ float sDts[CLEN * 12];    // [l][r]
    __shared__ float sDel[CLEN * 64];    // [l][dl]
    __shared__ float sU[CLEN * 64];      // [l][dl]

    int blk = blockIdx.x;                 // ((bk*CH + c)*6 + dblk)
    int dblk = blk % 6;
    int tmp = blk / 6;
    int c = tmp % CH;
    int bk = tmp / CH;
    int k = bk & 3, b = bk >> 2;
    int tid = threadIdx.x;
    int l0 = c * CLEN;

    {
        const float4* Bg = (const float4*)(Bsb + ((size_t)bk * LL + l0) * NN);
        const float4* Cg = (const float4*)(Csb + ((size_t)bk * LL + l0) * NN);
        if (tid < CLEN * 4) {
            ((float4*)sB)[tid] = Bg[tid];
            ((float4*)sC)[tid] = Cg[tid];
        }
        const float4* Dg = (const float4*)(dts + ((size_t)bk * LL + l0) * RR);
        for (int i = tid; i < CLEN * 3; i += 256)
            ((float4*)sDts)[i] = Dg[i];
    }
    {
        const float* xb = xcT + (size_t)b * LL * DI + dblk * 64;
        #pragma unroll
        for (int it = 0; it < 3; ++it) {
            int i = it * 256 + tid;       // 768 float4
            int l = i >> 4, f4 = i & 15;
            int pos = pos_for(k, l0 + l);
            ((float4*)sU)[l * 16 + f4] = *(const float4*)(xb + (size_t)pos * DI + f4 * 4);
        }
    }
    __syncthreads();
    {
        int dl = tid & 63, lset = tid >> 6;
        int dd = dblk * 64 + dl;
        int kdq = k * DI + dd;
        float dtbv = dtb_g[kdq];
        float w12[12];
        {
            const float4* p = (const float4*)(dtw_g + (size_t)kdq * RR);
            float4 a0 = p[0], a1 = p[1], a2 = p[2];
            w12[0]=a0.x; w12[1]=a0.y; w12[2]=a0.z;  w12[3]=a0.w;
            w12[4]=a1.x; w12[5]=a1.y; w12[6]=a1.z;  w12[7]=a1.w;
            w12[8]=a2.x; w12[9]=a2.y; w12[10]=a2.z; w12[11]=a2.w;
        }
        #pragma unroll
        for (int j = 0; j < 12; ++j) {
            int l = lset * 12 + j;
            const float* dp = sDts + l * 12;
            float acc = dtbv;
            #pragma unroll
            for (int r = 0; r < 12; ++r) acc += dp[r] * w12[r];
            sDel[l * 64 + dl] = softplus_f(acc);
        }
    }
    __syncthreads();

    int lane = tid & 63, wv = tid >> 6;
    int q = lane & 3;
    int d16 = lane >> 2;
    int dl = wv * 16 + d16;
    int d = dblk * 64 + dl;
    int kd = k * DI + d;
    int n0 = q << 2;

    float4 Al = *(const float4*)(Alogs + (size_t)kd * NN + n0);
    float A2[4] = { -expf(Al.x) * LOG2E, -expf(Al.y) * LOG2E,
                    -expf(Al.z) * LOG2E, -expf(Al.w) * LOG2E };
    float Dv = Ds_g[kd];
    float* Sc = Sbuf + ((size_t)bk * LL + l0 + q) * DI + d;
    float* yc = yk   + ((size_t)bk * LL + l0 + q) * DI + d;

    float h0 = 0.f, h1 = 0.f, h2 = 0.f, h3 = 0.f;
    float td = 0.f;
    float yhold = 0.f, Shold = 0.f;

    #pragma unroll
    for (int l = 0; l < CLEN; ++l) {
        float delta = sDel[l * 64 + dl];
        float ub_b  = sU[l * 64 + dl];
        td += delta;
        float du = delta * ub_b;
        float4 B4 = *(const float4*)&sB[l * 16 + n0];
        h0 = h0 * fexp2(delta * A2[0]) + du * B4.x;
        h1 = h1 * fexp2(delta * A2[1]) + du * B4.y;
        h2 = h2 * fexp2(delta * A2[2]) + du * B4.z;
        h3 = h3 * fexp2(delta * A2[3]) + du * B4.w;
        float4 C4 = *(const float4*)&sC[l * 16 + n0];
        float yp = h0 * C4.x + h1 * C4.y + h2 * C4.z + h3 * C4.w;
        yp += dpp_movf<0xB1>(yp);
        yp += dpp_movf<0x4E>(yp);
        float yf = yp + ub_b * Dv;
        if (q == (l & 3)) { yhold = yf; Shold = td; }
        if ((l & 3) == 3) {
            *yc = yhold; *Sc = Shold;
            yc += 4 * DI; Sc += 4 * DI;
        }
    }

    float4 h4; h4.x = h0; h4.y = h1; h4.z = h2; h4.w = h3;
    *(float4*)(hstin + ((size_t)(bk * CH + c) * DI + d) * NN + n0) = h4;
}

// ---------------- combine (in-place): end-states -> incoming states
__global__ __launch_bounds__(256) void k_scan_combine(
    float* __restrict__ hstin,
    const float* __restrict__ Sbuf,
    const float* __restrict__ Alogs)
{
    int t = blockIdx.x * 256 + threadIdx.x;   // B*K*DI*NN = 98304
    int n = t & 15;
    int d = (t >> 4) % DI;
    int bk = t / (DI * NN);
    int k = bk & 3;
    float A2 = -expf(Alogs[(size_t)(k * DI + d) * NN + n]) * LOG2E;
    float h = 0.f;
    for (int c = 0; c < CH; ++c) {
        size_t rb = (size_t)(bk * CH + c) * DI + d;
        float hend = hstin[rb * NN + n];
        hstin[rb * NN + n] = h;
        float St = Sbuf[((size_t)bk * LL + c * CLEN + CLEN - 1) * DI + d];
        h = fexp2(A2 * St) * h + hend;
    }
}

// ---------------- correction: stage C,S in LDS, plain RMW on exclusive region
__global__ __launch_bounds__(256) void k_corr(
    const float* __restrict__ Csb,
    const float* __restrict__ Sbuf,
    const float* __restrict__ hin,
    const float* __restrict__ Alogs,
    float* __restrict__ yk)
{
    __shared__ float sC[CLEN * 16];      // [l][n]
    __shared__ float sS[CLEN * 64];      // [l][dl]

    int blk = blockIdx.x;                 // ((bk*CH + c)*6 + dblk)
    int dblk = blk % 6;
    int tmp = blk / 6;
    int c = tmp % CH;
    if (c == 0) return;
    int bk = tmp / CH;
    int k = bk & 3;
    int tid = threadIdx.x;
    int l0 = c * CLEN;

    {
        const float4* Cg = (const float4*)(Csb + ((size_t)bk * LL + l0) * NN);
        if (tid < CLEN * 4) ((float4*)sC)[tid] = Cg[tid];
        const float* Sg = Sbuf + ((size_t)bk * LL + l0) * DI + dblk * 64;
        #pragma unroll
        for (int it = 0; it < 3; ++it) {
            int i = it * 256 + tid;       // 768 float4
            int l = i >> 4, f4 = i & 15;
            ((float4*)sS)[l * 16 + f4] = *(const float4*)(Sg + (size_t)l * DI + f4 * 4);
        }
    }
    __syncthreads();

    int lane = tid & 63, wv = tid >> 6;
    int q = lane & 3;
    int d16 = lane >> 2;
    int dl = wv * 16 + d16;
    int d = dblk * 64 + dl;
    int kd = k * DI + d;
    int n0 = q << 2;

    float4 Al = *(const float4*)(Alogs + (size_t)kd * NN + n0);
    float A2[4] = { -expf(Al.x) * LOG2E, -expf(Al.y) * LOG2E,
                    -expf(Al.z) * LOG2E, -expf(Al.w) * LOG2E };
    float4 H4 = *(const float4*)(hin + ((size_t)(bk * CH + c) * DI + d) * NN + n0);
    float* yc = yk + ((size_t)bk * LL + l0 + q) * DI + d;

    float ychold = 0.f;
    #pragma unroll
    for (int l = 0; l < CLEN; ++l) {
        float S = sS[l * 64 + dl];
        float4 C4 = *(const float4*)&sC[l * 16 + n0];
        float yv = C4.x * fexp2(A2[0] * S) * H4.x
                 + C4.y * fexp2(A2[1] * S) * H4.y
                 + C4.z * fexp2(A2[2] * S) * H4.z
                 + C4.w * fexp2(A2[3] * S) * H4.w;
        yv += dpp_movf<0xB1>(yv);
        yv += dpp_movf<0x4E>(yv);
        if (q == (l & 3)) ychold = yv;
        if ((l & 3) == 3) {
            *yc += ychold;
            yc += 4 * DI;
        }
    }
}

// ---------------- merge (CrossMerge) + LayerNorm + gate -> bf16 gbuf
__global__ __launch_bounds__(384) void k_merge_ln_gate(
    const float* __restrict__ yk,
    const float* __restrict__ xcz,     // z at columns 384..767
    const float* __restrict__ lnw,
    const float* __restrict__ lnb,
    short* __restrict__ gbufb)
{
    int pg = blockIdx.x;            // b*LL + pos
    int b = pg / LL;
    int pos = pg % LL;
    int d = threadIdx.x;
    int pt = (pos % 48) * 48 + pos / 48;

    const float* y0 = yk + ((size_t)(b * 4 + 0) * LL + pos) * DI;
    const float* y1 = yk + ((size_t)(b * 4 + 1) * LL + pt) * DI;
    const float* y2 = yk + ((size_t)(b * 4 + 2) * LL + (LL - 1 - pos)) * DI;
    const float* y3 = yk + ((size_t)(b * 4 + 3) * LL + (LL - 1 - pt)) * DI;
    float v = y0[d] + y1[d] + y2[d] + y3[d];

    float s = v, qq = v * v;
    #pragma unroll
    for (int o = 32; o >= 1; o >>= 1) {
        s += __shfl_xor(s, o, 64);
        qq += __shfl_xor(qq, o, 64);
    }
    __shared__ float ssum[6], sqq[6];
    int lane = d & 63, w = d >> 6;
    if (lane == 0) { ssum[w] = s; sqq[w] = qq; }
    __syncthreads();
    float ts = 0.f, tq = 0.f;
    #pragma unroll
    for (int i = 0; i < 6; ++i) { ts += ssum[i]; tq += sqq[i]; }
    float mu = ts / (float)DI;
    float var = tq / (float)DI - mu * mu;
    float inv = rsqrtf(var + 1e-5f);
    float y = (v - mu) * inv * lnw[d] + lnb[d];
    float z = xcz[(size_t)pg * 768 + DI + d];
    gbufb[(size_t)pg * DI + d] = f2bf(y * z);
}

// ---------------- K6: out_proj via bf16 MFMA. K=384, tile 128l x 64o.
__global__ __launch_bounds__(256) void k_outproj_mfma(
    const short* __restrict__ gbufb,   // (B,L,384) bf16
    const short* __restrict__ owbf,    // (192,384) bf16
    float* __restrict__ out)           // (B,192,L) fp32
{
    __shared__ short sA[128 * 40];
    __shared__ short sB[64 * 40];
    int o0 = blockIdx.x * 64;
    int l0 = blockIdx.y * 128;
    int b  = blockIdx.z;
    int tid = threadIdx.x;
    int lane = tid & 63, wid = tid >> 6;
    int n = lane & 15, quad = lane >> 4;

    v4f acc[2][4];
    #pragma unroll
    for (int i = 0; i < 2; ++i)
        #pragma unroll
        for (int j = 0; j < 4; ++j) acc[i][j] = (v4f){0.f, 0.f, 0.f, 0.f};

    for (int kc = 0; kc < DI; kc += 32) {
        for (int i = tid; i < 512; i += 256) {
            int row = i >> 2, seg = i & 3;
            *(v8s*)&sA[row * 40 + seg * 8] =
                *(const v8s*)(gbufb + (size_t)(b * LL + l0 + row) * DI + kc + seg * 8);
        }
        {
            int row = tid >> 2, seg = tid & 3;
            *(v8s*)&sB[row * 40 + seg * 8] =
                *(const v8s*)(owbf + (size_t)(o0 + row) * DI + kc + seg * 8);
        }
        __syncthreads();
        v8s a0 = *(v8s*)&sA[(wid * 32 + n) * 40 + quad * 8];
        v8s a1 = *(v8s*)&sA[(wid * 32 + 16 + n) * 40 + quad * 8];
        #pragma unroll
        for (int os = 0; os < 4; ++os) {
            v8s bv = *(v8s*)&sB[(os * 16 + n) * 40 + quad * 8];
            acc[0][os] = __builtin_amdgcn_mfma_f32_16x16x32_bf16(a0, bv, acc[0][os], 0, 0, 0);
            acc[1][os] = __builtin_amdgcn_mfma_f32_16x16x32_bf16(a1, bv, acc[1][os], 0, 0, 0);
        }
        __syncthreads();
    }
    #pragma unroll
    for (int ls = 0; ls < 2; ++ls)
        #pragma unroll
        for (int os = 0; os < 4; ++os) {
            int o = o0 + os * 16 + n;
            #pragma unroll
            for (int r = 0; r < 4; ++r) {
                int l = l0 + wid * 32 + ls * 16 + quad * 4 + r;
                out[(size_t)(b * DM + o) * LL + l] = acc[ls][os][r];
            }
        }
}

extern "C" void kernel_launch(void* const* d_in, const int* in_sizes, int n_in,
                              void* d_out, int out_size, void* d_ws, size_t ws_size,
                              hipStream_t stream) {
    (void)in_sizes; (void)n_in; (void)out_size; (void)ws_size;
    const float* x      = (const float*)d_in[0];
    const float* ipw    = (const float*)d_in[1];
    const float* cw     = (const float*)d_in[2];
    const float* cb     = (const float*)d_in[3];
    const float* xpw    = (const float*)d_in[4];
    const float* dtw    = (const float*)d_in[5];
    const float* dtb    = (const float*)d_in[6];
    const float* Alogs  = (const float*)d_in[7];
    const float* Ds     = (const float*)d_in[8];
    const float* lnw    = (const float*)d_in[9];
    const float* lnb    = (const float*)d_in[10];
    const float* opw    = (const float*)d_in[11];
    float* out = (float*)d_out;

    float* wsf = (float*)d_ws;
    const size_t XCZ = (size_t)BQ * LL * 768;             //  7,077,888
    const size_t SZ  = (size_t)BQ * DI * LL;              //  3,538,944
    const size_t DTS = (size_t)BQ * KK * LL * RR;         //    442,368
    const size_t BCS = (size_t)BQ * KK * LL * NN;         //    589,824
    const size_t SBF = (size_t)BQ * KK * LL * DI;         // 14,155,776
    const size_t HST = (size_t)BQ * KK * CH * DI * NN;    //  4,718,592

    float* xcz   = wsf;                  // (B,L,768): xc half + gelu(z) half
    float* xcT   = xcz + XCZ;            // (B,L,384) fp32 conv output (scan u)
    float* dts   = xcT + SZ;             // (B,K,L,R)
    float* Bsb   = dts + DTS;            // (B,K,L,N)
    float* Csb   = Bsb + BCS;            // (B,K,L,N)
    float* Sbuf  = Csb + BCS;            // (B,K,L,DI)
    float* hstin = Sbuf + SBF;           // (B,K,CH,DI,N)
    float* yk    = hstin + HST;          // (B,K,L,DI)
    short* xTbf  = (short*)(yk + SBF);   // (B,L,192) bf16 in_proj input
    short* wibf  = xTbf + (size_t)BQ * LL * DM;   // (768,192)
    short* owbf  = wibf + 768 * 192;              // (192,384)
    short* wpbf  = owbf + 192 * 384;              // (192,384) x_proj padded
    // gbufb (B*L*384 shorts) aliases Sbuf: Sbuf's last reader k_corr finishes
    // before k_merge_ln_gate writes. xcTbf (B*L*384 shorts) aliases yk: xcTbf
    // dead after k_xproj_mfma; yk first written by k_scan_pass1 (after).
    short* gbufb = (short*)Sbuf;
    short* xcTbf = (short*)yk;

    k_prep_w<<<1152, 256, 0, stream>>>(ipw, opw, xpw, wibf, owbf, wpbf);
    k_prep_xT<<<BQ * 72 * 6, 256, 0, stream>>>(x, xTbf);
    k_inproj_mfma<<<dim3(12, 18, BQ), 256, 0, stream>>>(xTbf, wibf, xcz);
    k_dwconv<<<BQ * HH * 4, 384, 0, stream>>>(xcz, cw, cb, xcT, xcTbf);
    k_xproj_mfma<<<dim3(3, 18, BQ), 256, 0, stream>>>(xcTbf, wpbf, dts, Bsb, Csb);

    k_scan_pass1<<<BQ * KK * CH * 6, 256, 0, stream>>>(
        xcT, dts, Bsb, Csb, dtw, dtb, Alogs, Ds, Sbuf, hstin, yk);
    k_scan_combine<<<(BQ * KK * DI * NN) / 256, 256, 0, stream>>>(
        hstin, Sbuf, Alogs);
    k_corr<<<BQ * KK * CH * 6, 256, 0, stream>>>(Csb, Sbuf, hstin, Alogs, yk);
    k_merge_ln_gate<<<BQ * LL, 384, 0, stream>>>(yk, xcz, lnw, lnb, gbufb);

    k_outproj_mfma<<<dim3(3, 18, BQ), 256, 0, stream>>>(gbufb, owbf, out);
}